// Round 1
// baseline (9449.580 us; speedup 1.0000x reference)
//
#include <hip/hip_runtime.h>

typedef unsigned short u16;
typedef unsigned int   u32;

#define B_     4
#define L_     392
#define T_     1568   // B_*L_
#define DM     384
#define DI     768
#define DS     16
#define DTR    24
#define DEPTH_ 24
#define NPATCH 196

typedef __bf16 bf16x8 __attribute__((ext_vector_type(8)));
typedef float  f32x4  __attribute__((ext_vector_type(4)));

__device__ __forceinline__ u16 f2bf(float f) {
  union { float f; u32 u; } v; v.f = f;
  return (u16)((v.u + 0x7fffu + ((v.u >> 16) & 1u)) >> 16);  // RNE
}

// ---------------- fp32 -> bf16 bulk convert ----------------
__global__ __launch_bounds__(256) void cvt_kernel(const float* __restrict__ in,
                                                  u16* __restrict__ out, int n) {
  int i = blockIdx.x * 256 + threadIdx.x;
  if (i < n) out[i] = f2bf(in[i]);
}

// ---------------- im2col for patch embed (both z and x) ----------------
__global__ __launch_bounds__(256) void imcol_kernel(const float* __restrict__ z,
                                                    const float* __restrict__ x,
                                                    u16* __restrict__ out) {
  int idx = blockIdx.x * 256 + threadIdx.x;        // t*768 + k
  int t = idx / 768, k = idx - t * 768;
  int b = t / L_, l = t - b * L_;
  const float* img = (l < NPATCH) ? z : x;
  int p  = (l < NPATCH) ? l : l - NPATCH;
  int py = p / 14, px = p - py * 14;
  int ic = k >> 8, rem = k & 255, i = rem >> 4, j = rem & 15;
  float v = img[((size_t)b * 3 + ic) * 50176 + (size_t)(py * 16 + i) * 224 + (px * 16 + j)];
  out[idx] = f2bf(v);
}

// ---------------- generic bf16 MFMA GEMM: out[M,N] = A[M,K] * W[N,K]^T ----------------
// mode 0: store, mode 1: out +=
__global__ __launch_bounds__(256) void gemm_bf16(const u16* __restrict__ A,
                                                 const u16* __restrict__ W,
                                                 float* __restrict__ out,
                                                 int M, int N, int K, int mode) {
  int wave = threadIdx.x >> 6;
  int lane = threadIdx.x & 63;
  int r = lane & 15, quad = lane >> 4;
  int m_base = blockIdx.x * 64;
  int n_base = blockIdx.y * 64 + wave * 16;

  const u16* aptr[4];
#pragma unroll
  for (int mi = 0; mi < 4; ++mi) {
    int row = m_base + mi * 16 + r; if (row > M - 1) row = M - 1;
    aptr[mi] = A + (size_t)row * K + quad * 8;
  }
  int wcol = n_base + r; if (wcol > N - 1) wcol = N - 1;
  const u16* wptr = W + (size_t)wcol * K + quad * 8;

  f32x4 acc[4] = {f32x4{0,0,0,0}, f32x4{0,0,0,0}, f32x4{0,0,0,0}, f32x4{0,0,0,0}};
  for (int k0 = 0; k0 < K; k0 += 32) {
    bf16x8 bfrag = *(const bf16x8*)(wptr + k0);
#pragma unroll
    for (int mi = 0; mi < 4; ++mi) {
      bf16x8 afrag = *(const bf16x8*)(aptr[mi] + k0);
      acc[mi] = __builtin_amdgcn_mfma_f32_16x16x32_bf16(afrag, bfrag, acc[mi], 0, 0, 0);
    }
  }
  int ccol = n_base + r;
  if (ccol < N) {
#pragma unroll
    for (int mi = 0; mi < 4; ++mi) {
#pragma unroll
      for (int rr = 0; rr < 4; ++rr) {
        int crow = m_base + mi * 16 + quad * 4 + rr;
        if (crow < M) {
          size_t o = (size_t)crow * N + ccol;
          if (mode) out[o] += acc[mi][rr]; else out[o] = acc[mi][rr];
        }
      }
    }
  }
}

// ---------------- add patch bias + positional embedding ----------------
__global__ __launch_bounds__(256) void biaspos_kernel(float* __restrict__ h,
                                                      const float* __restrict__ pb,
                                                      const float* __restrict__ pos) {
  int idx = blockIdx.x * 256 + threadIdx.x;  // t*384 + c
  int t = idx / DM, c = idx - t * DM;
  int p = (t % L_) % NPATCH;
  h[idx] += pb[c] + pos[(size_t)(1 + p) * DM + c];
}

// ---------------- LayerNorm over DM per token ----------------
__global__ __launch_bounds__(384) void ln_kernel(const float* __restrict__ x,
                                                 const float* __restrict__ w,
                                                 const float* __restrict__ b,
                                                 u16* __restrict__ out_bf,
                                                 float* __restrict__ out_f, int to_bf) {
  int t = blockIdx.x;
  int i = threadIdx.x;
  float v = x[(size_t)t * DM + i];
  float s = v, s2 = v * v;
#pragma unroll
  for (int o = 32; o; o >>= 1) { s += __shfl_xor(s, o); s2 += __shfl_xor(s2, o); }
  __shared__ float ls[6], ls2[6];
  int wv = i >> 6;
  if ((i & 63) == 0) { ls[wv] = s; ls2[wv] = s2; }
  __syncthreads();
  float ts = 0.f, ts2 = 0.f;
#pragma unroll
  for (int j = 0; j < 6; ++j) { ts += ls[j]; ts2 += ls2[j]; }
  float mu  = ts * (1.f / DM);
  float var = ts2 * (1.f / DM) - mu * mu;
  float rs  = rsqrtf(var + 1e-5f);
  float o   = (v - mu) * rs * w[i] + b[i];
  if (to_bf) out_bf[(size_t)t * DM + i] = f2bf(o);
  else       out_f[(size_t)t * DM + i]  = o;
}

// ---------------- causal conv3 + SiLU ----------------
__global__ __launch_bounds__(256) void conv_kernel(const float* __restrict__ xz,
                                                   const float* __restrict__ cw,
                                                   const float* __restrict__ cb,
                                                   float* __restrict__ xcf,
                                                   u16* __restrict__ xcb) {
  int idx = blockIdx.x * 256 + threadIdx.x;  // t*768 + d
  int t = idx / DI, d = idx - t * DI;
  int l = t % L_;
  float w0 = cw[d * 3 + 0], w1 = cw[d * 3 + 1], w2 = cw[d * 3 + 2];
  float acc = cb[d] + w2 * xz[(size_t)t * (2 * DI) + d];
  if (l >= 1) acc += w1 * xz[(size_t)(t - 1) * (2 * DI) + d];
  if (l >= 2) acc += w0 * xz[(size_t)(t - 2) * (2 * DI) + d];
  float v = acc / (1.f + __expf(-acc));   // silu
  xcf[idx] = v;
  xcb[idx] = f2bf(v);
}

// ---------------- dt projection (K=24) + softplus ----------------
__global__ __launch_bounds__(256) void dt_kernel(const float* __restrict__ dbl,
                                                 const float* __restrict__ dw,
                                                 const float* __restrict__ db,
                                                 float* __restrict__ dt) {
  int idx = blockIdx.x * 256 + threadIdx.x;  // t*768 + d
  int t = idx / DI, d = idx - t * DI;
  float s = db[d];
  const float* dr = dbl + (size_t)t * 56;
  const float* wr = dw + (size_t)d * DTR;
#pragma unroll
  for (int r = 0; r < DTR; ++r) s += dr[r] * wr[r];
  dt[idx] = (s > 20.f) ? s : log1pf(__expf(s));
}

// ---------------- selective scan: thread per (b,d,n), 16-lane reduce ----------------
__global__ __launch_bounds__(256) void scan_kernel(const float* __restrict__ dt,
                                                   const float* __restrict__ xc,
                                                   const float* __restrict__ xz,
                                                   const float* __restrict__ dbl,
                                                   const float* __restrict__ Alog,
                                                   const float* __restrict__ Dp,
                                                   u16* __restrict__ y) {
  int g  = blockIdx.x * 256 + threadIdx.x;   // [0, 4*768*16)
  int n  = g & 15;
  int bd = g >> 4;
  int d  = bd % DI;
  int b  = bd / DI;
  float A  = -__expf(Alog[(size_t)d * DS + n]);
  float Dd = Dp[d];
  const float* dtp = dt  + (size_t)(b * L_) * DI + d;
  const float* xcp = xc  + (size_t)(b * L_) * DI + d;
  const float* zgp = xz  + (size_t)(b * L_) * (2 * DI) + DI + d;
  const float* Bp  = dbl + (size_t)(b * L_) * 56 + DTR + n;
  const float* Cp  = dbl + (size_t)(b * L_) * 56 + DTR + DS + n;
  u16* yp = y + (size_t)(b * L_) * DI + d;
  float h = 0.f;
  for (int l = 0; l < L_; ++l) {
    float dtv = dtp[0], xcv = xcp[0], Bv = Bp[0], Cv = Cp[0];
    float dA = __expf(dtv * A);
    h = dA * h + dtv * xcv * Bv;
    float p = h * Cv;
    p += __shfl_xor(p, 1); p += __shfl_xor(p, 2);
    p += __shfl_xor(p, 4); p += __shfl_xor(p, 8);
    if (n == 0) {
      float zgv = zgp[0];
      float yv  = (p + Dd * xcv) * (zgv / (1.f + __expf(-zgv)));
      yp[0] = f2bf(yv);
    }
    dtp += DI; xcp += DI; zgp += 2 * DI; Bp += 56; Cp += 56; yp += DI;
  }
}

extern "C" void kernel_launch(void* const* d_in, const int* in_sizes, int n_in,
                              void* d_out, int out_size, void* d_ws, size_t ws_size,
                              hipStream_t stream) {
  const float* z      = (const float*)d_in[0];
  const float* x      = (const float*)d_in[1];
  const float* patchW = (const float*)d_in[2];
  const float* patchB = (const float*)d_in[3];
  const float* pos    = (const float*)d_in[4];
  const float* normW  = (const float*)d_in[5];
  const float* normB  = (const float*)d_in[6];
  const float* inW    = (const float*)d_in[7];
  const float* convW  = (const float*)d_in[8];
  const float* convB  = (const float*)d_in[9];
  const float* xprojW = (const float*)d_in[10];
  const float* dtW    = (const float*)d_in[11];
  const float* dtB    = (const float*)d_in[12];
  const float* Alog   = (const float*)d_in[13];
  const float* Dpar   = (const float*)d_in[14];
  const float* outW   = (const float*)d_in[15];
  const float* fnW    = (const float*)d_in[16];
  const float* fnB    = (const float*)d_in[17];
  float* out = (float*)d_out;

  char* base = (char*)d_ws; size_t off = 0;
  auto alloc = [&](size_t bytes) {
    void* p = base + off; off = (off + bytes + 255) & ~(size_t)255; return p;
  };
  float* h    = (float*)alloc((size_t)T_ * DM * 4);
  u16*   lnb  = (u16*)  alloc((size_t)T_ * DM * 2);
  float* xz   = (float*)alloc((size_t)T_ * 2 * DI * 4);
  float* xcf  = (float*)alloc((size_t)T_ * DI * 4);
  u16*   xcb  = (u16*)  alloc((size_t)T_ * DI * 2);
  float* dbl  = (float*)alloc((size_t)T_ * 56 * 4);
  float* dt   = (float*)alloc((size_t)T_ * DI * 4);
  u16*   yb   = (u16*)  alloc((size_t)T_ * DI * 2);
  u16*   imcol= (u16*)  alloc((size_t)T_ * 768 * 2);
  u16*   pwB  = (u16*)  alloc((size_t)DM * 768 * 2);
  u16*   inWb = (u16*)  alloc((size_t)DEPTH_ * 2 * DI * DM * 2);
  u16*   xpWb = (u16*)  alloc((size_t)DEPTH_ * 56 * DI * 2);
  u16*   outWb= (u16*)  alloc((size_t)DEPTH_ * DM * DI * 2);

  // one-time (per call) weight conversion fp32 -> bf16
  {
    size_t n;
    n = (size_t)DM * 768;
    cvt_kernel<<<dim3((n + 255) / 256), 256, 0, stream>>>(patchW, pwB, (int)n);
    n = (size_t)DEPTH_ * 2 * DI * DM;
    cvt_kernel<<<dim3((n + 255) / 256), 256, 0, stream>>>(inW, inWb, (int)n);
    n = (size_t)DEPTH_ * 56 * DI;
    cvt_kernel<<<dim3((n + 255) / 256), 256, 0, stream>>>(xprojW, xpWb, (int)n);
    n = (size_t)DEPTH_ * DM * DI;
    cvt_kernel<<<dim3((n + 255) / 256), 256, 0, stream>>>(outW, outWb, (int)n);
  }

  // patch embed: im2col + GEMM + bias/pos
  imcol_kernel<<<dim3(T_ * 768 / 256), 256, 0, stream>>>(z, x, imcol);
  gemm_bf16<<<dim3((T_ + 63) / 64, DM / 64), 256, 0, stream>>>(imcol, pwB, h, T_, DM, 768, 0);
  biaspos_kernel<<<dim3(T_ * DM / 256), 256, 0, stream>>>(h, patchB, pos);

  for (int ly = 0; ly < DEPTH_; ++ly) {
    ln_kernel<<<dim3(T_), dim3(DM), 0, stream>>>(h, normW + (size_t)ly * DM, normB + (size_t)ly * DM,
                                                 lnb, (float*)nullptr, 1);
    gemm_bf16<<<dim3((T_ + 63) / 64, (2 * DI) / 64), 256, 0, stream>>>(
        lnb, inWb + (size_t)ly * 2 * DI * DM, xz, T_, 2 * DI, DM, 0);
    conv_kernel<<<dim3(T_ * DI / 256), 256, 0, stream>>>(
        xz, convW + (size_t)ly * DI * 3, convB + (size_t)ly * DI, xcf, xcb);
    gemm_bf16<<<dim3((T_ + 63) / 64, 1), 256, 0, stream>>>(
        xcb, xpWb + (size_t)ly * 56 * DI, dbl, T_, 56, DI, 0);
    dt_kernel<<<dim3(T_ * DI / 256), 256, 0, stream>>>(
        dbl, dtW + (size_t)ly * DI * DTR, dtB + (size_t)ly * DI, dt);
    scan_kernel<<<dim3(B_ * DI * DS / 256), 256, 0, stream>>>(
        dt, xcf, xz, dbl, Alog + (size_t)ly * DI * DS, Dpar + (size_t)ly * DI, yb);
    gemm_bf16<<<dim3((T_ + 63) / 64, DM / 64), 256, 0, stream>>>(
        yb, outWb + (size_t)ly * DM * DI, h, T_, DM, DI, 1);
  }

  ln_kernel<<<dim3(T_), dim3(DM), 0, stream>>>(h, fnW, fnB, (u16*)nullptr, out, 0);
}

// Round 2
// 4153.406 us; speedup vs baseline: 2.2751x; 2.2751x over previous
//
#include <hip/hip_runtime.h>

typedef unsigned short u16;
typedef unsigned int   u32;

#define B_     4
#define L_     392
#define T_     1568   // B_*L_
#define DM     384
#define DI     768
#define DS     16
#define DTR    24
#define DEPTH_ 24
#define NPATCH 196
#define NC     14    // scan chunks
#define CL     28    // chunk length (NC*CL == L_)

typedef __bf16 bf16x8 __attribute__((ext_vector_type(8)));
typedef float  f32x4  __attribute__((ext_vector_type(4)));

__device__ __forceinline__ u16 f2bf(float f) {
  union { float f; u32 u; } v; v.f = f;
  return (u16)((v.u + 0x7fffu + ((v.u >> 16) & 1u)) >> 16);  // RNE
}

// ---------------- fp32 -> bf16 bulk convert ----------------
__global__ __launch_bounds__(256) void cvt_kernel(const float* __restrict__ in,
                                                  u16* __restrict__ out, int n) {
  int i = blockIdx.x * 256 + threadIdx.x;
  if (i < n) out[i] = f2bf(in[i]);
}

// ---------------- im2col for patch embed (both z and x) ----------------
__global__ __launch_bounds__(256) void imcol_kernel(const float* __restrict__ z,
                                                    const float* __restrict__ x,
                                                    u16* __restrict__ out) {
  int idx = blockIdx.x * 256 + threadIdx.x;        // t*768 + k
  int t = idx / 768, k = idx - t * 768;
  int b = t / L_, l = t - b * L_;
  const float* img = (l < NPATCH) ? z : x;
  int p  = (l < NPATCH) ? l : l - NPATCH;
  int py = p / 14, px = p - py * 14;
  int ic = k >> 8, rem = k & 255, i = rem >> 4, j = rem & 15;
  float v = img[((size_t)b * 3 + ic) * 50176 + (size_t)(py * 16 + i) * 224 + (px * 16 + j)];
  out[idx] = f2bf(v);
}

// ---------------- generic bf16 MFMA GEMM: out[M,N] = A[M,K] * W[N,K]^T ----------------
// mode 0: store, mode 1: out +=
__global__ __launch_bounds__(256) void gemm_bf16(const u16* __restrict__ A,
                                                 const u16* __restrict__ W,
                                                 float* __restrict__ out,
                                                 int M, int N, int K, int mode) {
  int wave = threadIdx.x >> 6;
  int lane = threadIdx.x & 63;
  int r = lane & 15, quad = lane >> 4;
  int m_base = blockIdx.x * 64;
  int n_base = blockIdx.y * 64 + wave * 16;

  const u16* aptr[4];
#pragma unroll
  for (int mi = 0; mi < 4; ++mi) {
    int row = m_base + mi * 16 + r; if (row > M - 1) row = M - 1;
    aptr[mi] = A + (size_t)row * K + quad * 8;
  }
  int wcol = n_base + r; if (wcol > N - 1) wcol = N - 1;
  const u16* wptr = W + (size_t)wcol * K + quad * 8;

  f32x4 acc[4] = {f32x4{0,0,0,0}, f32x4{0,0,0,0}, f32x4{0,0,0,0}, f32x4{0,0,0,0}};
  for (int k0 = 0; k0 < K; k0 += 32) {
    bf16x8 bfrag = *(const bf16x8*)(wptr + k0);
#pragma unroll
    for (int mi = 0; mi < 4; ++mi) {
      bf16x8 afrag = *(const bf16x8*)(aptr[mi] + k0);
      acc[mi] = __builtin_amdgcn_mfma_f32_16x16x32_bf16(afrag, bfrag, acc[mi], 0, 0, 0);
    }
  }
  int ccol = n_base + r;
  if (ccol < N) {
#pragma unroll
    for (int mi = 0; mi < 4; ++mi) {
#pragma unroll
      for (int rr = 0; rr < 4; ++rr) {
        int crow = m_base + mi * 16 + quad * 4 + rr;
        if (crow < M) {
          size_t o = (size_t)crow * N + ccol;
          if (mode) out[o] += acc[mi][rr]; else out[o] = acc[mi][rr];
        }
      }
    }
  }
}

// ---------------- add patch bias + positional embedding ----------------
__global__ __launch_bounds__(256) void biaspos_kernel(float* __restrict__ h,
                                                      const float* __restrict__ pb,
                                                      const float* __restrict__ pos) {
  int idx = blockIdx.x * 256 + threadIdx.x;  // t*384 + c
  int t = idx / DM, c = idx - t * DM;
  int p = (t % L_) % NPATCH;
  h[idx] += pb[c] + pos[(size_t)(1 + p) * DM + c];
}

// ---------------- LayerNorm over DM per token ----------------
__global__ __launch_bounds__(384) void ln_kernel(const float* __restrict__ x,
                                                 const float* __restrict__ w,
                                                 const float* __restrict__ b,
                                                 u16* __restrict__ out_bf,
                                                 float* __restrict__ out_f, int to_bf) {
  int t = blockIdx.x;
  int i = threadIdx.x;
  float v = x[(size_t)t * DM + i];
  float s = v, s2 = v * v;
#pragma unroll
  for (int o = 32; o; o >>= 1) { s += __shfl_xor(s, o); s2 += __shfl_xor(s2, o); }
  __shared__ float ls[6], ls2[6];
  int wv = i >> 6;
  if ((i & 63) == 0) { ls[wv] = s; ls2[wv] = s2; }
  __syncthreads();
  float ts = 0.f, ts2 = 0.f;
#pragma unroll
  for (int j = 0; j < 6; ++j) { ts += ls[j]; ts2 += ls2[j]; }
  float mu  = ts * (1.f / DM);
  float var = ts2 * (1.f / DM) - mu * mu;
  float rs  = rsqrtf(var + 1e-5f);
  float o   = (v - mu) * rs * w[i] + b[i];
  if (to_bf) out_bf[(size_t)t * DM + i] = f2bf(o);
  else       out_f[(size_t)t * DM + i]  = o;
}

// ---------------- causal conv3 + SiLU ----------------
__global__ __launch_bounds__(256) void conv_kernel(const float* __restrict__ xz,
                                                   const float* __restrict__ cw,
                                                   const float* __restrict__ cb,
                                                   float* __restrict__ xcf,
                                                   u16* __restrict__ xcb) {
  int idx = blockIdx.x * 256 + threadIdx.x;  // t*768 + d
  int t = idx / DI, d = idx - t * DI;
  int l = t % L_;
  float w0 = cw[d * 3 + 0], w1 = cw[d * 3 + 1], w2 = cw[d * 3 + 2];
  float acc = cb[d] + w2 * xz[(size_t)t * (2 * DI) + d];
  if (l >= 1) acc += w1 * xz[(size_t)(t - 1) * (2 * DI) + d];
  if (l >= 2) acc += w0 * xz[(size_t)(t - 2) * (2 * DI) + d];
  float v = acc / (1.f + __expf(-acc));   // silu
  xcf[idx] = v;
  xcb[idx] = f2bf(v);
}

// ---------------- dt projection (K=24) + softplus ----------------
__global__ __launch_bounds__(256) void dt_kernel(const float* __restrict__ dbl,
                                                 const float* __restrict__ dw,
                                                 const float* __restrict__ db,
                                                 float* __restrict__ dt) {
  int idx = blockIdx.x * 256 + threadIdx.x;  // t*768 + d
  int t = idx / DI, d = idx - t * DI;
  float s = db[d];
  const float* dr = dbl + (size_t)t * 56;
  const float* wr = dw + (size_t)d * DTR;
#pragma unroll
  for (int r = 0; r < DTR; ++r) s += dr[r] * wr[r];
  dt[idx] = (s > 20.f) ? s : log1pf(__expf(s));
}

// ---------------- chunked selective scan, one block per (b,d) ----------------
// 256 threads: tid = c*16 + n (c = chunk 0..13 valid, n = state 0..15).
// Pass A: per-chunk (P = prod dA, S = local scan end). Combine: 16 threads
// walk the 14 chunks serially (composition rule h <- P*h + S), storing chunk
// entry states. Pass B: re-run each chunk from its entry state, reduce over
// n via shfl (n occupies the low 4 lane bits), emit gated y.
__global__ __launch_bounds__(256) void scan_kernel(const float* __restrict__ dt,
                                                   const float* __restrict__ xc,
                                                   const float* __restrict__ xz,
                                                   const float* __restrict__ dbl,
                                                   const float* __restrict__ Alog,
                                                   const float* __restrict__ Dp,
                                                   u16* __restrict__ y) {
  int bd = blockIdx.x;          // b*DI + d
  int d  = bd % DI;
  int b  = bd / DI;
  int tid = threadIdx.x;
  int n = tid & 15, c = tid >> 4;   // c in [0,16), valid work for c < NC

  __shared__ float Psh[NC][DS], Ssh[NC][DS], Hsh[NC][DS];

  float A  = -__expf(Alog[(size_t)d * DS + n]);
  float Dd = Dp[d];

  int t0 = b * L_ + c * CL;
  const float* dtp = dt  + (size_t)t0 * DI + d;
  const float* xcp = xc  + (size_t)t0 * DI + d;
  const float* Bp  = dbl + (size_t)t0 * 56 + DTR + n;
  const float* Cp  = dbl + (size_t)t0 * 56 + DTR + DS + n;

  if (c < NC) {
    float P = 1.f, S = 0.f;
#pragma unroll 4
    for (int l = 0; l < CL; ++l) {
      float dtv = dtp[l * DI], xcv = xcp[l * DI], Bv = Bp[l * 56];
      float dA = __expf(dtv * A);
      P *= dA;
      S = dA * S + dtv * xcv * Bv;
    }
    Psh[c][n] = P; Ssh[c][n] = S;
  }
  __syncthreads();
  if (tid < DS) {   // thread n: serial combine over chunks
    float h = 0.f;
#pragma unroll
    for (int cc = 0; cc < NC; ++cc) {
      Hsh[cc][tid] = h;
      h = Psh[cc][tid] * h + Ssh[cc][tid];
    }
  }
  __syncthreads();
  if (c < NC) {
    float h = Hsh[c][n];
    const float* zgp = xz + (size_t)t0 * (2 * DI) + DI + d;
    u16* yp = y + (size_t)t0 * DI + d;
#pragma unroll 4
    for (int l = 0; l < CL; ++l) {
      float dtv = dtp[l * DI], xcv = xcp[l * DI], Bv = Bp[l * 56], Cv = Cp[l * 56];
      float dA = __expf(dtv * A);
      h = dA * h + dtv * xcv * Bv;
      float p = h * Cv;
      p += __shfl_xor(p, 1); p += __shfl_xor(p, 2);
      p += __shfl_xor(p, 4); p += __shfl_xor(p, 8);
      if (n == 0) {
        float zgv = zgp[l * 2 * DI];
        float yv  = (p + Dd * xcv) * (zgv / (1.f + __expf(-zgv)));
        yp[l * DI] = f2bf(yv);
      }
    }
  }
}

extern "C" void kernel_launch(void* const* d_in, const int* in_sizes, int n_in,
                              void* d_out, int out_size, void* d_ws, size_t ws_size,
                              hipStream_t stream) {
  const float* z      = (const float*)d_in[0];
  const float* x      = (const float*)d_in[1];
  const float* patchW = (const float*)d_in[2];
  const float* patchB = (const float*)d_in[3];
  const float* pos    = (const float*)d_in[4];
  const float* normW  = (const float*)d_in[5];
  const float* normB  = (const float*)d_in[6];
  const float* inW    = (const float*)d_in[7];
  const float* convW  = (const float*)d_in[8];
  const float* convB  = (const float*)d_in[9];
  const float* xprojW = (const float*)d_in[10];
  const float* dtW    = (const float*)d_in[11];
  const float* dtB    = (const float*)d_in[12];
  const float* Alog   = (const float*)d_in[13];
  const float* Dpar   = (const float*)d_in[14];
  const float* outW   = (const float*)d_in[15];
  const float* fnW    = (const float*)d_in[16];
  const float* fnB    = (const float*)d_in[17];
  float* out = (float*)d_out;

  char* base = (char*)d_ws; size_t off = 0;
  auto alloc = [&](size_t bytes) {
    void* p = base + off; off = (off + bytes + 255) & ~(size_t)255; return p;
  };
  float* h    = (float*)alloc((size_t)T_ * DM * 4);
  u16*   lnb  = (u16*)  alloc((size_t)T_ * DM * 2);
  float* xz   = (float*)alloc((size_t)T_ * 2 * DI * 4);
  float* xcf  = (float*)alloc((size_t)T_ * DI * 4);
  u16*   xcb  = (u16*)  alloc((size_t)T_ * DI * 2);
  float* dbl  = (float*)alloc((size_t)T_ * 56 * 4);
  float* dt   = (float*)alloc((size_t)T_ * DI * 4);
  u16*   yb   = (u16*)  alloc((size_t)T_ * DI * 2);
  u16*   imcol= (u16*)  alloc((size_t)T_ * 768 * 2);
  u16*   pwB  = (u16*)  alloc((size_t)DM * 768 * 2);
  u16*   inWb = (u16*)  alloc((size_t)DEPTH_ * 2 * DI * DM * 2);
  u16*   xpWb = (u16*)  alloc((size_t)DEPTH_ * 56 * DI * 2);
  u16*   outWb= (u16*)  alloc((size_t)DEPTH_ * DM * DI * 2);

  // one-time (per call) weight conversion fp32 -> bf16
  {
    size_t n;
    n = (size_t)DM * 768;
    cvt_kernel<<<dim3((n + 255) / 256), 256, 0, stream>>>(patchW, pwB, (int)n);
    n = (size_t)DEPTH_ * 2 * DI * DM;
    cvt_kernel<<<dim3((n + 255) / 256), 256, 0, stream>>>(inW, inWb, (int)n);
    n = (size_t)DEPTH_ * 56 * DI;
    cvt_kernel<<<dim3((n + 255) / 256), 256, 0, stream>>>(xprojW, xpWb, (int)n);
    n = (size_t)DEPTH_ * DM * DI;
    cvt_kernel<<<dim3((n + 255) / 256), 256, 0, stream>>>(outW, outWb, (int)n);
  }

  // patch embed: im2col + GEMM + bias/pos
  imcol_kernel<<<dim3(T_ * 768 / 256), 256, 0, stream>>>(z, x, imcol);
  gemm_bf16<<<dim3((T_ + 63) / 64, DM / 64), 256, 0, stream>>>(imcol, pwB, h, T_, DM, 768, 0);
  biaspos_kernel<<<dim3(T_ * DM / 256), 256, 0, stream>>>(h, patchB, pos);

  for (int ly = 0; ly < DEPTH_; ++ly) {
    ln_kernel<<<dim3(T_), dim3(DM), 0, stream>>>(h, normW + (size_t)ly * DM, normB + (size_t)ly * DM,
                                                 lnb, (float*)nullptr, 1);
    gemm_bf16<<<dim3((T_ + 63) / 64, (2 * DI) / 64), 256, 0, stream>>>(
        lnb, inWb + (size_t)ly * 2 * DI * DM, xz, T_, 2 * DI, DM, 0);
    conv_kernel<<<dim3(T_ * DI / 256), 256, 0, stream>>>(
        xz, convW + (size_t)ly * DI * 3, convB + (size_t)ly * DI, xcf, xcb);
    gemm_bf16<<<dim3((T_ + 63) / 64, 1), 256, 0, stream>>>(
        xcb, xpWb + (size_t)ly * 56 * DI, dbl, T_, 56, DI, 0);
    dt_kernel<<<dim3(T_ * DI / 256), 256, 0, stream>>>(
        dbl, dtW + (size_t)ly * DI * DTR, dtB + (size_t)ly * DI, dt);
    scan_kernel<<<dim3(B_ * DI), 256, 0, stream>>>(
        dt, xcf, xz, dbl, Alog + (size_t)ly * DI * DS, Dpar + (size_t)ly * DI, yb);
    gemm_bf16<<<dim3((T_ + 63) / 64, DM / 64), 256, 0, stream>>>(
        yb, outWb + (size_t)ly * DM * DI, h, T_, DM, DI, 1);
  }

  ln_kernel<<<dim3(T_), dim3(DM), 0, stream>>>(h, fnW, fnB, (u16*)nullptr, out, 0);
}

// Round 3
// 3791.199 us; speedup vs baseline: 2.4925x; 1.0955x over previous
//
#include <hip/hip_runtime.h>

typedef unsigned short u16;
typedef unsigned int   u32;

#define B_     4
#define L_     392
#define T_     1568   // B_*L_
#define DM     384
#define DI     768
#define DS     16
#define DTR    24
#define DEPTH_ 24
#define NPATCH 196
#define NC     14    // scan chunks
#define CL     28    // chunk length (NC*CL == L_)

typedef __bf16 bf16x8 __attribute__((ext_vector_type(8)));
typedef float  f32x4  __attribute__((ext_vector_type(4)));

__device__ __forceinline__ u16 f2bf(float f) {
  union { float f; u32 u; } v; v.f = f;
  return (u16)((v.u + 0x7fffu + ((v.u >> 16) & 1u)) >> 16);  // RNE
}
__device__ __forceinline__ float bf2f(u16 h) {
  union { u32 u; float f; } v; v.u = (u32)h << 16; return v.f;
}

// ---------------- fp32 -> bf16 bulk convert ----------------
__global__ __launch_bounds__(256) void cvt_kernel(const float* __restrict__ in,
                                                  u16* __restrict__ out, int n) {
  int i = blockIdx.x * 256 + threadIdx.x;
  if (i < n) out[i] = f2bf(in[i]);
}

// ---------------- im2col for patch embed (both z and x) ----------------
__global__ __launch_bounds__(256) void imcol_kernel(const float* __restrict__ z,
                                                    const float* __restrict__ x,
                                                    u16* __restrict__ out) {
  int idx = blockIdx.x * 256 + threadIdx.x;        // t*768 + k
  int t = idx / 768, k = idx - t * 768;
  int b = t / L_, l = t - b * L_;
  const float* img = (l < NPATCH) ? z : x;
  int p  = (l < NPATCH) ? l : l - NPATCH;
  int py = p / 14, px = p - py * 14;
  int ic = k >> 8, rem = k & 255, i = rem >> 4, j = rem & 15;
  float v = img[((size_t)b * 3 + ic) * 50176 + (size_t)(py * 16 + i) * 224 + (px * 16 + j)];
  out[idx] = f2bf(v);
}

// ---------------- generic bf16 MFMA GEMM: out[M,N] = A[M,K] * W[N,K]^T ----------------
// mode 0: fp32 store, mode 1: fp32 +=, mode 2: bf16 store
__global__ __launch_bounds__(256) void gemm_bf16(const u16* __restrict__ A,
                                                 const u16* __restrict__ W,
                                                 float* __restrict__ outf,
                                                 u16* __restrict__ outb,
                                                 int M, int N, int K, int mode) {
  int wave = threadIdx.x >> 6;
  int lane = threadIdx.x & 63;
  int r = lane & 15, quad = lane >> 4;
  int m_base = blockIdx.x * 64;
  int n_base = blockIdx.y * 64 + wave * 16;

  const u16* aptr[4];
#pragma unroll
  for (int mi = 0; mi < 4; ++mi) {
    int row = m_base + mi * 16 + r; if (row > M - 1) row = M - 1;
    aptr[mi] = A + (size_t)row * K + quad * 8;
  }
  int wcol = n_base + r; if (wcol > N - 1) wcol = N - 1;
  const u16* wptr = W + (size_t)wcol * K + quad * 8;

  f32x4 acc[4] = {f32x4{0,0,0,0}, f32x4{0,0,0,0}, f32x4{0,0,0,0}, f32x4{0,0,0,0}};
  for (int k0 = 0; k0 < K; k0 += 32) {
    bf16x8 bfrag = *(const bf16x8*)(wptr + k0);
#pragma unroll
    for (int mi = 0; mi < 4; ++mi) {
      bf16x8 afrag = *(const bf16x8*)(aptr[mi] + k0);
      acc[mi] = __builtin_amdgcn_mfma_f32_16x16x32_bf16(afrag, bfrag, acc[mi], 0, 0, 0);
    }
  }
  int ccol = n_base + r;
  if (ccol < N) {
#pragma unroll
    for (int mi = 0; mi < 4; ++mi) {
#pragma unroll
      for (int rr = 0; rr < 4; ++rr) {
        int crow = m_base + mi * 16 + quad * 4 + rr;
        if (crow < M) {
          size_t o = (size_t)crow * N + ccol;
          if (mode == 0)      outf[o] = acc[mi][rr];
          else if (mode == 1) outf[o] += acc[mi][rr];
          else                outb[o] = f2bf(acc[mi][rr]);
        }
      }
    }
  }
}

// ---------------- add patch bias + positional embedding ----------------
__global__ __launch_bounds__(256) void biaspos_kernel(float* __restrict__ h,
                                                      const float* __restrict__ pb,
                                                      const float* __restrict__ pos) {
  int idx = blockIdx.x * 256 + threadIdx.x;  // t*384 + c
  int t = idx / DM, c = idx - t * DM;
  int p = (t % L_) % NPATCH;
  h[idx] += pb[c] + pos[(size_t)(1 + p) * DM + c];
}

// ---------------- LayerNorm over DM per token ----------------
__global__ __launch_bounds__(384) void ln_kernel(const float* __restrict__ x,
                                                 const float* __restrict__ w,
                                                 const float* __restrict__ b,
                                                 u16* __restrict__ out_bf,
                                                 float* __restrict__ out_f, int to_bf) {
  int t = blockIdx.x;
  int i = threadIdx.x;
  float v = x[(size_t)t * DM + i];
  float s = v, s2 = v * v;
#pragma unroll
  for (int o = 32; o; o >>= 1) { s += __shfl_xor(s, o); s2 += __shfl_xor(s2, o); }
  __shared__ float ls[6], ls2[6];
  int wv = i >> 6;
  if ((i & 63) == 0) { ls[wv] = s; ls2[wv] = s2; }
  __syncthreads();
  float ts = 0.f, ts2 = 0.f;
#pragma unroll
  for (int j = 0; j < 6; ++j) { ts += ls[j]; ts2 += ls2[j]; }
  float mu  = ts * (1.f / DM);
  float var = ts2 * (1.f / DM) - mu * mu;
  float rs  = rsqrtf(var + 1e-5f);
  float o   = (v - mu) * rs * w[i] + b[i];
  if (to_bf) out_bf[(size_t)t * DM + i] = f2bf(o);
  else       out_f[(size_t)t * DM + i]  = o;
}

// ---------------- causal conv3 + SiLU, d-major in, dual-layout out ----------------
// reads xz_t[1536][T] bf16 (rows 0..DI-1 = xs); writes xc_t[d][t] bf16 (for scan)
// and xcb[t][d] bf16 (for x_proj GEMM) via LDS tile transpose.
__global__ __launch_bounds__(256) void conv_kernel(const u16* __restrict__ xzt,
                                                   const float* __restrict__ cw,
                                                   const float* __restrict__ cb,
                                                   u16* __restrict__ xct,
                                                   u16* __restrict__ xcb) {
  __shared__ u16 tile[64][66];
  int d0 = blockIdx.x * 64, t0 = blockIdx.y * 64;
  int tl = threadIdx.x & 63, dq = threadIdx.x >> 6;
  int t  = t0 + tl;
  int tc = (t < T_) ? t : T_ - 1;
  int l  = tc % L_;
#pragma unroll
  for (int i = 0; i < 16; ++i) {
    int dl = dq * 16 + i;
    int d  = d0 + dl;
    const u16* row = xzt + (size_t)d * T_ + tc;
    float acc = cb[d] + cw[d * 3 + 2] * bf2f(row[0]);
    if (l >= 1) acc += cw[d * 3 + 1] * bf2f(row[-1]);
    if (l >= 2) acc += cw[d * 3 + 0] * bf2f(row[-2]);
    float v = acc / (1.f + __expf(-acc));   // silu
    u16 bv = f2bf(v);
    if (t < T_) xct[(size_t)d * T_ + t] = bv;
    tile[dl][tl] = bv;
  }
  __syncthreads();
#pragma unroll
  for (int i = 0; i < 16; ++i) {
    int t2 = t0 + dq * 16 + i;
    if (t2 < T_) xcb[(size_t)t2 * DI + d0 + tl] = tile[tl][dq * 16 + i];
  }
}

// ---------------- dt projection (K=24) + softplus -> dt_t[d][t] fp32 ----------------
__global__ __launch_bounds__(256) void dt_kernel(const float* __restrict__ dbl,
                                                 const float* __restrict__ dw,
                                                 const float* __restrict__ db,
                                                 float* __restrict__ dtt) {
  int d0 = blockIdx.x * 64, t0 = blockIdx.y * 64;
  int tl = threadIdx.x & 63, dq = threadIdx.x >> 6;
  int t = t0 + tl;
  int tc = (t < T_) ? t : T_ - 1;
  float r[DTR];
  const float* dr = dbl + (size_t)tc * 56;
#pragma unroll
  for (int j = 0; j < DTR; ++j) r[j] = dr[j];
  if (t < T_) {
#pragma unroll
    for (int i = 0; i < 16; ++i) {
      int d = d0 + dq * 16 + i;
      const float* wr = dw + (size_t)d * DTR;
      float s = db[d];
#pragma unroll
      for (int j = 0; j < DTR; ++j) s += r[j] * wr[j];
      dtt[(size_t)d * T_ + t] = (s > 20.f) ? s : log1pf(__expf(s));
    }
  }
}

// ---------------- chunked selective scan, fully coalesced streams ----------------
// block per (b,d); threads (c,n). All per-(b,d) streams are contiguous rows.
__global__ __launch_bounds__(256) void scan_kernel(const float* __restrict__ dtt,
                                                   const u16* __restrict__ xct,
                                                   const u16* __restrict__ xzt,
                                                   const float* __restrict__ dbl,
                                                   const float* __restrict__ Alog,
                                                   const float* __restrict__ Dp,
                                                   u16* __restrict__ yt) {
  int bd = blockIdx.x;          // b*DI + d
  int d  = bd % DI;
  int b  = bd / DI;
  int tid = threadIdx.x;
  int n = tid & 15, c = tid >> 4;   // c in [0,16), valid for c < NC

  __shared__ float Psh[NC][DS], Ssh[NC][DS], Hsh[NC][DS];
  __shared__ u16 ysh[L_];

  float A  = -__expf(Alog[(size_t)d * DS + n]);
  float Dd = Dp[d];

  int tb = b * L_ + c * CL;
  const float* dtp = dtt + (size_t)d * T_ + tb;
  const u16*   xcp = xct + (size_t)d * T_ + tb;
  const u16*   zgp = xzt + (size_t)(DI + d) * T_ + tb;
  const float* Bp  = dbl + (size_t)tb * 56 + DTR + n;
  const float* Cp  = Bp + DS;

  if (c < NC) {
    float P = 1.f, S = 0.f;
#pragma unroll 4
    for (int l = 0; l < CL; ++l) {
      float dtv = dtp[l], xcv = bf2f(xcp[l]), Bv = Bp[l * 56];
      float dA = __expf(dtv * A);
      P *= dA;
      S = dA * S + dtv * xcv * Bv;
    }
    Psh[c][n] = P; Ssh[c][n] = S;
  }
  __syncthreads();
  if (tid < DS) {   // thread n: serial combine over chunks
    float hh = 0.f;
#pragma unroll
    for (int cc = 0; cc < NC; ++cc) {
      Hsh[cc][tid] = hh;
      hh = Psh[cc][tid] * hh + Ssh[cc][tid];
    }
  }
  __syncthreads();
  if (c < NC) {
    float hh = Hsh[c][n];
#pragma unroll 4
    for (int l = 0; l < CL; ++l) {
      float dtv = dtp[l], xcv = bf2f(xcp[l]), Bv = Bp[l * 56], Cv = Cp[l * 56];
      float dA = __expf(dtv * A);
      hh = dA * hh + dtv * xcv * Bv;
      float p = hh * Cv;
      p += __shfl_xor(p, 1); p += __shfl_xor(p, 2);
      p += __shfl_xor(p, 4); p += __shfl_xor(p, 8);
      if (n == 0) {
        float zgv = bf2f(zgp[l]);
        ysh[c * CL + l] = f2bf((p + Dd * xcv) * (zgv / (1.f + __expf(-zgv))));
      }
    }
  }
  __syncthreads();
  if (tid < 196) {  // 392 u16 = 196 dwords, contiguous coalesced row store
    ((u32*)(yt + (size_t)d * T_ + b * L_))[tid] = ((const u32*)ysh)[tid];
  }
}

// ---------------- y_t[d][t] -> y[t][d] bf16 tile transpose ----------------
__global__ __launch_bounds__(256) void ytr_kernel(const u16* __restrict__ yt,
                                                  u16* __restrict__ y) {
  __shared__ u16 tile[64][66];
  int d0 = blockIdx.x * 64, t0 = blockIdx.y * 64;
  int tl = threadIdx.x & 63, dq = threadIdx.x >> 6;
  int t = t0 + tl;
  int tc = (t < T_) ? t : T_ - 1;
#pragma unroll
  for (int i = 0; i < 16; ++i) {
    int dl = dq * 16 + i;
    tile[dl][tl] = yt[(size_t)(d0 + dl) * T_ + tc];
  }
  __syncthreads();
#pragma unroll
  for (int i = 0; i < 16; ++i) {
    int t2 = t0 + dq * 16 + i;
    if (t2 < T_) y[(size_t)t2 * DI + d0 + tl] = tile[tl][dq * 16 + i];
  }
}

extern "C" void kernel_launch(void* const* d_in, const int* in_sizes, int n_in,
                              void* d_out, int out_size, void* d_ws, size_t ws_size,
                              hipStream_t stream) {
  const float* z      = (const float*)d_in[0];
  const float* x      = (const float*)d_in[1];
  const float* patchW = (const float*)d_in[2];
  const float* patchB = (const float*)d_in[3];
  const float* pos    = (const float*)d_in[4];
  const float* normW  = (const float*)d_in[5];
  const float* normB  = (const float*)d_in[6];
  const float* inW    = (const float*)d_in[7];
  const float* convW  = (const float*)d_in[8];
  const float* convB  = (const float*)d_in[9];
  const float* xprojW = (const float*)d_in[10];
  const float* dtW    = (const float*)d_in[11];
  const float* dtB    = (const float*)d_in[12];
  const float* Alog   = (const float*)d_in[13];
  const float* Dpar   = (const float*)d_in[14];
  const float* outW   = (const float*)d_in[15];
  const float* fnW    = (const float*)d_in[16];
  const float* fnB    = (const float*)d_in[17];
  float* out = (float*)d_out;

  char* base = (char*)d_ws; size_t off = 0;
  auto alloc = [&](size_t bytes) {
    void* p = base + off; off = (off + bytes + 255) & ~(size_t)255; return p;
  };
  float* h    = (float*)alloc((size_t)T_ * DM * 4);
  u16*   lnb  = (u16*)  alloc((size_t)T_ * DM * 2);
  u16*   xzt  = (u16*)  alloc((size_t)2 * DI * T_ * 2);   // [1536][T] bf16
  u16*   xct  = (u16*)  alloc((size_t)DI * T_ * 2);       // [DI][T] bf16
  u16*   xcb  = (u16*)  alloc((size_t)T_ * DI * 2);       // [T][DI] bf16
  float* dbl  = (float*)alloc((size_t)T_ * 56 * 4);
  float* dtt  = (float*)alloc((size_t)DI * T_ * 4);       // [DI][T] fp32
  u16*   yt   = (u16*)  alloc((size_t)DI * T_ * 2);       // [DI][T] bf16
  u16*   yb   = (u16*)  alloc((size_t)T_ * DI * 2);       // [T][DI] bf16
  u16*   imcol= (u16*)  alloc((size_t)T_ * 768 * 2);
  u16*   pwB  = (u16*)  alloc((size_t)DM * 768 * 2);
  u16*   inWb = (u16*)  alloc((size_t)DEPTH_ * 2 * DI * DM * 2);
  u16*   xpWb = (u16*)  alloc((size_t)DEPTH_ * 56 * DI * 2);
  u16*   outWb= (u16*)  alloc((size_t)DEPTH_ * DM * DI * 2);

  // one-time (per call) weight conversion fp32 -> bf16
  {
    size_t n;
    n = (size_t)DM * 768;
    cvt_kernel<<<dim3((n + 255) / 256), 256, 0, stream>>>(patchW, pwB, (int)n);
    n = (size_t)DEPTH_ * 2 * DI * DM;
    cvt_kernel<<<dim3((n + 255) / 256), 256, 0, stream>>>(inW, inWb, (int)n);
    n = (size_t)DEPTH_ * 56 * DI;
    cvt_kernel<<<dim3((n + 255) / 256), 256, 0, stream>>>(xprojW, xpWb, (int)n);
    n = (size_t)DEPTH_ * DM * DI;
    cvt_kernel<<<dim3((n + 255) / 256), 256, 0, stream>>>(outW, outWb, (int)n);
  }

  // patch embed: im2col + GEMM + bias/pos
  imcol_kernel<<<dim3(T_ * 768 / 256), 256, 0, stream>>>(z, x, imcol);
  gemm_bf16<<<dim3((T_ + 63) / 64, DM / 64), 256, 0, stream>>>(
      imcol, pwB, h, (u16*)nullptr, T_, DM, 768, 0);
  biaspos_kernel<<<dim3(T_ * DM / 256), 256, 0, stream>>>(h, patchB, pos);

  const int TG = (T_ + 63) / 64;  // 25
  for (int ly = 0; ly < DEPTH_; ++ly) {
    ln_kernel<<<dim3(T_), dim3(DM), 0, stream>>>(h, normW + (size_t)ly * DM, normB + (size_t)ly * DM,
                                                 lnb, (float*)nullptr, 1);
    // swapped: xz_t[1536][T] = inW[1536,384] · ln[T,384]^T, bf16 out
    gemm_bf16<<<dim3((2 * DI) / 64, TG), 256, 0, stream>>>(
        inWb + (size_t)ly * 2 * DI * DM, lnb, (float*)nullptr, xzt, 2 * DI, T_, DM, 2);
    conv_kernel<<<dim3(DI / 64, TG), 256, 0, stream>>>(
        xzt, convW + (size_t)ly * DI * 3, convB + (size_t)ly * DI, xct, xcb);
    gemm_bf16<<<dim3(TG, 1), 256, 0, stream>>>(
        xcb, xpWb + (size_t)ly * 56 * DI, dbl, (u16*)nullptr, T_, 56, DI, 0);
    dt_kernel<<<dim3(DI / 64, TG), 256, 0, stream>>>(
        dbl, dtW + (size_t)ly * DI * DTR, dtB + (size_t)ly * DI, dtt);
    scan_kernel<<<dim3(B_ * DI), 256, 0, stream>>>(
        dtt, xct, xzt, dbl, Alog + (size_t)ly * DI * DS, Dpar + (size_t)ly * DI, yt);
    ytr_kernel<<<dim3(DI / 64, TG), 256, 0, stream>>>(yt, yb);
    gemm_bf16<<<dim3(TG, DM / 64), 256, 0, stream>>>(
        yb, outWb + (size_t)ly * DM * DI, h, (u16*)nullptr, T_, DM, DI, 1);
  }

  ln_kernel<<<dim3(T_), dim3(DM), 0, stream>>>(h, fnW, fnB, (u16*)nullptr, out, 0);
}

// Round 4
// 3731.496 us; speedup vs baseline: 2.5324x; 1.0160x over previous
//
#include <hip/hip_runtime.h>

typedef unsigned short u16;
typedef unsigned int   u32;

#define B_     4
#define L_     392
#define T_     1568   // B_*L_
#define DM     384
#define DI     768
#define DS     16
#define DTR    24
#define DEPTH_ 24
#define NPATCH 196
#define NC     14    // scan chunks
#define CL     28    // chunk length (NC*CL == L_)

typedef __bf16 bf16x8 __attribute__((ext_vector_type(8)));
typedef float  f32x4  __attribute__((ext_vector_type(4)));

__device__ __forceinline__ u16 f2bf(float f) {
  union { float f; u32 u; } v; v.f = f;
  return (u16)((v.u + 0x7fffu + ((v.u >> 16) & 1u)) >> 16);  // RNE
}
__device__ __forceinline__ float bf2f(u16 h) {
  union { u32 u; float f; } v; v.u = (u32)h << 16; return v.f;
}

// ---------------- fp32 -> bf16 bulk convert, 4 segments in one launch ----------------
__global__ __launch_bounds__(256) void cvt4_kernel(const float* __restrict__ s0, u16* __restrict__ o0, int n0,
                                                   const float* __restrict__ s1, u16* __restrict__ o1, int n1,
                                                   const float* __restrict__ s2, u16* __restrict__ o2, int n2,
                                                   const float* __restrict__ s3, u16* __restrict__ o3, int n3) {
  int i = blockIdx.x * 256 + threadIdx.x;
  if (i < n0) { o0[i] = f2bf(s0[i]); return; }
  i -= n0;
  if (i < n1) { o1[i] = f2bf(s1[i]); return; }
  i -= n1;
  if (i < n2) { o2[i] = f2bf(s2[i]); return; }
  i -= n2;
  if (i < n3) { o3[i] = f2bf(s3[i]); }
}

// ---------------- im2col for patch embed (both z and x) ----------------
__global__ __launch_bounds__(256) void imcol_kernel(const float* __restrict__ z,
                                                    const float* __restrict__ x,
                                                    u16* __restrict__ out) {
  int idx = blockIdx.x * 256 + threadIdx.x;        // t*768 + k
  int t = idx / 768, k = idx - t * 768;
  int b = t / L_, l = t - b * L_;
  const float* img = (l < NPATCH) ? z : x;
  int p  = (l < NPATCH) ? l : l - NPATCH;
  int py = p / 14, px = p - py * 14;
  int ic = k >> 8, rem = k & 255, i = rem >> 4, j = rem & 15;
  float v = img[((size_t)b * 3 + ic) * 50176 + (size_t)(py * 16 + i) * 224 + (px * 16 + j)];
  out[idx] = f2bf(v);
}

// ---------------- generic bf16 MFMA GEMM: out[M,N] = A[M,K] * W[N,K]^T ----------------
// mode 0: fp32 store, mode 1: fp32 +=, mode 2: bf16 store
__global__ __launch_bounds__(256) void gemm_bf16(const u16* __restrict__ A,
                                                 const u16* __restrict__ W,
                                                 float* __restrict__ outf,
                                                 u16* __restrict__ outb,
                                                 int M, int N, int K, int mode) {
  int wave = threadIdx.x >> 6;
  int lane = threadIdx.x & 63;
  int r = lane & 15, quad = lane >> 4;
  int m_base = blockIdx.x * 64;
  int n_base = blockIdx.y * 64 + wave * 16;

  const u16* aptr[4];
#pragma unroll
  for (int mi = 0; mi < 4; ++mi) {
    int row = m_base + mi * 16 + r; if (row > M - 1) row = M - 1;
    aptr[mi] = A + (size_t)row * K + quad * 8;
  }
  int wcol = n_base + r; if (wcol > N - 1) wcol = N - 1;
  const u16* wptr = W + (size_t)wcol * K + quad * 8;

  f32x4 acc[4] = {f32x4{0,0,0,0}, f32x4{0,0,0,0}, f32x4{0,0,0,0}, f32x4{0,0,0,0}};
  for (int k0 = 0; k0 < K; k0 += 32) {
    bf16x8 bfrag = *(const bf16x8*)(wptr + k0);
#pragma unroll
    for (int mi = 0; mi < 4; ++mi) {
      bf16x8 afrag = *(const bf16x8*)(aptr[mi] + k0);
      acc[mi] = __builtin_amdgcn_mfma_f32_16x16x32_bf16(afrag, bfrag, acc[mi], 0, 0, 0);
    }
  }
  int ccol = n_base + r;
  if (ccol < N) {
#pragma unroll
    for (int mi = 0; mi < 4; ++mi) {
#pragma unroll
      for (int rr = 0; rr < 4; ++rr) {
        int crow = m_base + mi * 16 + quad * 4 + rr;
        if (crow < M) {
          size_t o = (size_t)crow * N + ccol;
          if (mode == 0)      outf[o] = acc[mi][rr];
          else if (mode == 1) outf[o] += acc[mi][rr];
          else                outb[o] = f2bf(acc[mi][rr]);
        }
      }
    }
  }
}

// ---------------- add patch bias + positional embedding ----------------
__global__ __launch_bounds__(256) void biaspos_kernel(float* __restrict__ h,
                                                      const float* __restrict__ pb,
                                                      const float* __restrict__ pos) {
  int idx = blockIdx.x * 256 + threadIdx.x;  // t*384 + c
  int t = idx / DM, c = idx - t * DM;
  int p = (t % L_) % NPATCH;
  h[idx] += pb[c] + pos[(size_t)(1 + p) * DM + c];
}

// ---------------- LayerNorm over DM per token ----------------
__global__ __launch_bounds__(384) void ln_kernel(const float* __restrict__ x,
                                                 const float* __restrict__ w,
                                                 const float* __restrict__ b,
                                                 u16* __restrict__ out_bf,
                                                 float* __restrict__ out_f, int to_bf) {
  int t = blockIdx.x;
  int i = threadIdx.x;
  float v = x[(size_t)t * DM + i];
  float s = v, s2 = v * v;
#pragma unroll
  for (int o = 32; o; o >>= 1) { s += __shfl_xor(s, o); s2 += __shfl_xor(s2, o); }
  __shared__ float ls[6], ls2[6];
  int wv = i >> 6;
  if ((i & 63) == 0) { ls[wv] = s; ls2[wv] = s2; }
  __syncthreads();
  float ts = 0.f, ts2 = 0.f;
#pragma unroll
  for (int j = 0; j < 6; ++j) { ts += ls[j]; ts2 += ls2[j]; }
  float mu  = ts * (1.f / DM);
  float var = ts2 * (1.f / DM) - mu * mu;
  float rs  = rsqrtf(var + 1e-5f);
  float o   = (v - mu) * rs * w[i] + b[i];
  if (to_bf) out_bf[(size_t)t * DM + i] = f2bf(o);
  else       out_f[(size_t)t * DM + i]  = o;
}

// ---------------- causal conv3 + SiLU, d-major in, dual-layout out ----------------
__global__ __launch_bounds__(256) void conv_kernel(const u16* __restrict__ xzt,
                                                   const float* __restrict__ cw,
                                                   const float* __restrict__ cb,
                                                   u16* __restrict__ xct,
                                                   u16* __restrict__ xcb) {
  __shared__ u16 tile[64][66];
  int d0 = blockIdx.x * 64, t0 = blockIdx.y * 64;
  int tl = threadIdx.x & 63, dq = threadIdx.x >> 6;
  int t  = t0 + tl;
  int tc = (t < T_) ? t : T_ - 1;
  int l  = tc % L_;
#pragma unroll
  for (int i = 0; i < 16; ++i) {
    int dl = dq * 16 + i;
    int d  = d0 + dl;
    const u16* row = xzt + (size_t)d * T_ + tc;
    float acc = cb[d] + cw[d * 3 + 2] * bf2f(row[0]);
    if (l >= 1) acc += cw[d * 3 + 1] * bf2f(row[-1]);
    if (l >= 2) acc += cw[d * 3 + 0] * bf2f(row[-2]);
    float v = acc / (1.f + __expf(-acc));   // silu
    u16 bv = f2bf(v);
    if (t < T_) xct[(size_t)d * T_ + t] = bv;
    tile[dl][tl] = bv;
  }
  __syncthreads();
#pragma unroll
  for (int i = 0; i < 16; ++i) {
    int t2 = t0 + dq * 16 + i;
    if (t2 < T_) xcb[(size_t)t2 * DI + d0 + tl] = tile[tl][dq * 16 + i];
  }
}

// ---------------- chunked selective scan with fused dt-proj + silu(z) ----------------
// block per (b,d); threads (c,n). Cooperative phase computes softplus(dt) and
// silu(zg) for all 392 tokens into LDS. Pass A caches dA/dBu in registers;
// pass B is pure recurrence + C-contraction.
__global__ __launch_bounds__(256) void scan_kernel(const u16* __restrict__ xct,
                                                   const u16* __restrict__ xzt,
                                                   const float* __restrict__ dbl,
                                                   const float* __restrict__ dtW,
                                                   const float* __restrict__ dtB,
                                                   const float* __restrict__ Alog,
                                                   const float* __restrict__ Dp,
                                                   u16* __restrict__ yt) {
  int bd = blockIdx.x;          // b*DI + d
  int d  = bd % DI;
  int b  = bd / DI;
  int tid = threadIdx.x;
  int n = tid & 15, c = tid >> 4;   // c in [0,16), valid for c < NC

  __shared__ float dtsh[L_];
  __shared__ float zsh[L_];
  __shared__ float Psh[NC][DS], Ssh[NC][DS], Hsh[NC][DS];
  __shared__ u16 ysh[L_];

  // cooperative: dt projection + softplus, silu(z)
  const float* wr = dtW + (size_t)d * DTR;   // block-uniform -> scalar loads
  float bias = dtB[d];
  const u16* zrow = xzt + (size_t)(DI + d) * T_ + b * L_;
  for (int l = tid; l < L_; l += 256) {
    const float* dr = dbl + (size_t)(b * L_ + l) * 56;
    float s = bias;
#pragma unroll
    for (int j = 0; j < DTR; ++j) s += dr[j] * wr[j];
    dtsh[l] = (s > 20.f) ? s : log1pf(__expf(s));
    float zv = bf2f(zrow[l]);
    zsh[l] = zv / (1.f + __expf(-zv));
  }
  float A  = -__expf(Alog[(size_t)d * DS + n]);
  float Dd = Dp[d];
  __syncthreads();

  int tb = b * L_ + c * CL;
  const u16*   xcp = xct + (size_t)d * T_ + tb;
  const float* Bp  = dbl + (size_t)tb * 56 + DTR + n;
  const float* Cp  = Bp + DS;

  float dA[CL], dBu[CL];
  if (c < NC) {
    float P = 1.f, S = 0.f;
#pragma unroll
    for (int l = 0; l < CL; ++l) {
      float dtv = dtsh[c * CL + l];        // LDS broadcast across n
      float xcv = bf2f(xcp[l]);
      float Bv  = Bp[l * 56];
      float e = __expf(dtv * A);
      float u = dtv * xcv * Bv;
      dA[l] = e; dBu[l] = u;
      P *= e;
      S = e * S + u;
    }
    Psh[c][n] = P; Ssh[c][n] = S;
  }
  __syncthreads();
  if (tid < DS) {   // thread n: serial combine over chunks
    float hh = 0.f;
#pragma unroll
    for (int cc = 0; cc < NC; ++cc) {
      Hsh[cc][tid] = hh;
      hh = Psh[cc][tid] * hh + Ssh[cc][tid];
    }
  }
  __syncthreads();
  if (c < NC) {
    float hh = Hsh[c][n];
#pragma unroll
    for (int l = 0; l < CL; ++l) {
      hh = dA[l] * hh + dBu[l];
      float p = hh * Cp[l * 56];
      p += __shfl_xor(p, 1); p += __shfl_xor(p, 2);
      p += __shfl_xor(p, 4); p += __shfl_xor(p, 8);
      if (n == 0) {
        float xcv = bf2f(xcp[l]);
        ysh[c * CL + l] = f2bf((p + Dd * xcv) * zsh[c * CL + l]);
      }
    }
  }
  __syncthreads();
  if (tid < 196) {  // 392 u16 = 196 dwords, contiguous coalesced row store
    ((u32*)(yt + (size_t)d * T_ + b * L_))[tid] = ((const u32*)ysh)[tid];
  }
}

// ---------------- y_t[d][t] -> y[t][d] bf16 tile transpose ----------------
__global__ __launch_bounds__(256) void ytr_kernel(const u16* __restrict__ yt,
                                                  u16* __restrict__ y) {
  __shared__ u16 tile[64][66];
  int d0 = blockIdx.x * 64, t0 = blockIdx.y * 64;
  int tl = threadIdx.x & 63, dq = threadIdx.x >> 6;
  int t = t0 + tl;
  int tc = (t < T_) ? t : T_ - 1;
#pragma unroll
  for (int i = 0; i < 16; ++i) {
    int dl = dq * 16 + i;
    tile[dl][tl] = yt[(size_t)(d0 + dl) * T_ + tc];
  }
  __syncthreads();
#pragma unroll
  for (int i = 0; i < 16; ++i) {
    int t2 = t0 + dq * 16 + i;
    if (t2 < T_) y[(size_t)t2 * DI + d0 + tl] = tile[tl][dq * 16 + i];
  }
}

extern "C" void kernel_launch(void* const* d_in, const int* in_sizes, int n_in,
                              void* d_out, int out_size, void* d_ws, size_t ws_size,
                              hipStream_t stream) {
  const float* z      = (const float*)d_in[0];
  const float* x      = (const float*)d_in[1];
  const float* patchW = (const float*)d_in[2];
  const float* patchB = (const float*)d_in[3];
  const float* pos    = (const float*)d_in[4];
  const float* normW  = (const float*)d_in[5];
  const float* normB  = (const float*)d_in[6];
  const float* inW    = (const float*)d_in[7];
  const float* convW  = (const float*)d_in[8];
  const float* convB  = (const float*)d_in[9];
  const float* xprojW = (const float*)d_in[10];
  const float* dtW    = (const float*)d_in[11];
  const float* dtB    = (const float*)d_in[12];
  const float* Alog   = (const float*)d_in[13];
  const float* Dpar   = (const float*)d_in[14];
  const float* outW   = (const float*)d_in[15];
  const float* fnW    = (const float*)d_in[16];
  const float* fnB    = (const float*)d_in[17];
  float* out = (float*)d_out;

  char* base = (char*)d_ws; size_t off = 0;
  auto alloc = [&](size_t bytes) {
    void* p = base + off; off = (off + bytes + 255) & ~(size_t)255; return p;
  };
  float* h    = (float*)alloc((size_t)T_ * DM * 4);
  u16*   lnb  = (u16*)  alloc((size_t)T_ * DM * 2);
  u16*   xzt  = (u16*)  alloc((size_t)2 * DI * T_ * 2);   // [1536][T] bf16
  u16*   xct  = (u16*)  alloc((size_t)DI * T_ * 2);       // [DI][T] bf16
  u16*   xcb  = (u16*)  alloc((size_t)T_ * DI * 2);       // [T][DI] bf16
  float* dbl  = (float*)alloc((size_t)T_ * 56 * 4);
  u16*   yt   = (u16*)  alloc((size_t)DI * T_ * 2);       // [DI][T] bf16
  u16*   yb   = (u16*)  alloc((size_t)T_ * DI * 2);       // [T][DI] bf16
  u16*   imcol= (u16*)  alloc((size_t)T_ * 768 * 2);
  u16*   pwB  = (u16*)  alloc((size_t)DM * 768 * 2);
  u16*   inWb = (u16*)  alloc((size_t)DEPTH_ * 2 * DI * DM * 2);
  u16*   xpWb = (u16*)  alloc((size_t)DEPTH_ * 56 * DI * 2);
  u16*   outWb= (u16*)  alloc((size_t)DEPTH_ * DM * DI * 2);

  // one-time (per call) weight conversion fp32 -> bf16, single launch
  {
    int n0 = DM * 768;
    int n1 = DEPTH_ * 2 * DI * DM;
    int n2 = DEPTH_ * 56 * DI;
    int n3 = DEPTH_ * DM * DI;
    int nt = n0 + n1 + n2 + n3;
    cvt4_kernel<<<dim3((nt + 255) / 256), 256, 0, stream>>>(
        patchW, pwB, n0, inW, inWb, n1, xprojW, xpWb, n2, outW, outWb, n3);
  }

  // patch embed: im2col + GEMM + bias/pos
  imcol_kernel<<<dim3(T_ * 768 / 256), 256, 0, stream>>>(z, x, imcol);
  gemm_bf16<<<dim3((T_ + 63) / 64, DM / 64), 256, 0, stream>>>(
      imcol, pwB, h, (u16*)nullptr, T_, DM, 768, 0);
  biaspos_kernel<<<dim3(T_ * DM / 256), 256, 0, stream>>>(h, patchB, pos);

  const int TG = (T_ + 63) / 64;  // 25
  for (int ly = 0; ly < DEPTH_; ++ly) {
    ln_kernel<<<dim3(T_), dim3(DM), 0, stream>>>(h, normW + (size_t)ly * DM, normB + (size_t)ly * DM,
                                                 lnb, (float*)nullptr, 1);
    // swapped: xz_t[1536][T] = inW[1536,384] · ln[T,384]^T, bf16 out
    gemm_bf16<<<dim3((2 * DI) / 64, TG), 256, 0, stream>>>(
        inWb + (size_t)ly * 2 * DI * DM, lnb, (float*)nullptr, xzt, 2 * DI, T_, DM, 2);
    conv_kernel<<<dim3(DI / 64, TG), 256, 0, stream>>>(
        xzt, convW + (size_t)ly * DI * 3, convB + (size_t)ly * DI, xct, xcb);
    gemm_bf16<<<dim3(TG, 1), 256, 0, stream>>>(
        xcb, xpWb + (size_t)ly * 56 * DI, dbl, (u16*)nullptr, T_, 56, DI, 0);
    scan_kernel<<<dim3(B_ * DI), 256, 0, stream>>>(
        xct, xzt, dbl, dtW + (size_t)ly * DI * DTR, dtB + (size_t)ly * DI,
        Alog + (size_t)ly * DI * DS, Dpar + (size_t)ly * DI, yt);
    ytr_kernel<<<dim3(DI / 64, TG), 256, 0, stream>>>(yt, yb);
    gemm_bf16<<<dim3(TG, DM / 64), 256, 0, stream>>>(
        yb, outWb + (size_t)ly * DM * DI, h, (u16*)nullptr, T_, DM, DI, 1);
  }

  ln_kernel<<<dim3(T_), dim3(DM), 0, stream>>>(h, fnW, fnB, (u16*)nullptr, out, 0);
}

// Round 5
// 3339.605 us; speedup vs baseline: 2.8296x; 1.1173x over previous
//
#include <hip/hip_runtime.h>

typedef unsigned short u16;
typedef unsigned int   u32;

#define B_     4
#define L_     392
#define T_     1568   // B_*L_
#define DM     384
#define DI     768
#define DS     16
#define DTR    24
#define DEPTH_ 24
#define NPATCH 196
#define NC     14    // scan chunks
#define CL     28    // chunk length (NC*CL == L_)

typedef __bf16 bf16x8 __attribute__((ext_vector_type(8)));
typedef float  f32x4  __attribute__((ext_vector_type(4)));
typedef u16    u16x4  __attribute__((ext_vector_type(4)));

__device__ __forceinline__ u16 f2bf(float f) {
  union { float f; u32 u; } v; v.f = f;
  return (u16)((v.u + 0x7fffu + ((v.u >> 16) & 1u)) >> 16);  // RNE
}
__device__ __forceinline__ float bf2f(u16 h) {
  union { u32 u; float f; } v; v.u = (u32)h << 16; return v.f;
}

// ---------------- fp32 -> bf16 bulk convert, vectorized, 4 segments ----------------
__global__ __launch_bounds__(256) void cvt4v_kernel(const float* __restrict__ s0, u16* __restrict__ o0, int m0,
                                                    const float* __restrict__ s1, u16* __restrict__ o1, int m1,
                                                    const float* __restrict__ s2, u16* __restrict__ o2, int m2,
                                                    const float* __restrict__ s3, u16* __restrict__ o3, int m3) {
  int i = blockIdx.x * 256 + threadIdx.x;   // index in float4 units
  const float* s; u16* o;
  if (i < m0)      { s = s0; o = o0; }
  else { i -= m0;
  if (i < m1)      { s = s1; o = o1; }
  else { i -= m1;
  if (i < m2)      { s = s2; o = o2; }
  else { i -= m2;
  if (i < m3)      { s = s3; o = o3; }
  else return; } } }
  float4 v = ((const float4*)s)[i];
  u16x4 r;
  r.x = f2bf(v.x); r.y = f2bf(v.y); r.z = f2bf(v.z); r.w = f2bf(v.w);
  ((u16x4*)o)[i] = r;
}

// ---------------- im2col for patch embed (both z and x) ----------------
__global__ __launch_bounds__(256) void imcol_kernel(const float* __restrict__ z,
                                                    const float* __restrict__ x,
                                                    u16* __restrict__ out) {
  int idx = blockIdx.x * 256 + threadIdx.x;        // t*768 + k
  int t = idx / 768, k = idx - t * 768;
  int b = t / L_, l = t - b * L_;
  const float* img = (l < NPATCH) ? z : x;
  int p  = (l < NPATCH) ? l : l - NPATCH;
  int py = p / 14, px = p - py * 14;
  int ic = k >> 8, rem = k & 255, i = rem >> 4, j = rem & 15;
  float v = img[((size_t)b * 3 + ic) * 50176 + (size_t)(py * 16 + i) * 224 + (px * 16 + j)];
  out[idx] = f2bf(v);
}

// ---------------- generic bf16 MFMA GEMM: out[M,N] = A[M,K] * W[N,K]^T ----------------
// mode 0: fp32 store, mode 1: fp32 +=, mode 2: bf16 store, mode 3: fp32 atomicAdd
// K is split across gridDim.z (requires mode 3 when gridDim.z > 1).
__global__ __launch_bounds__(256) void gemm_bf16(const u16* __restrict__ A,
                                                 const u16* __restrict__ W,
                                                 float* __restrict__ outf,
                                                 u16* __restrict__ outb,
                                                 int M, int N, int K, int mode) {
  int wave = threadIdx.x >> 6;
  int lane = threadIdx.x & 63;
  int r = lane & 15, quad = lane >> 4;
  int m_base = blockIdx.x * 64;
  int n_base = blockIdx.y * 64 + wave * 16;
  int kper = K / gridDim.z;
  int kbeg = blockIdx.z * kper;

  const u16* aptr[4];
#pragma unroll
  for (int mi = 0; mi < 4; ++mi) {
    int row = m_base + mi * 16 + r; if (row > M - 1) row = M - 1;
    aptr[mi] = A + (size_t)row * K + quad * 8;
  }
  int wcol = n_base + r; if (wcol > N - 1) wcol = N - 1;
  const u16* wptr = W + (size_t)wcol * K + quad * 8;

  f32x4 acc[4] = {f32x4{0,0,0,0}, f32x4{0,0,0,0}, f32x4{0,0,0,0}, f32x4{0,0,0,0}};
  for (int k0 = kbeg; k0 < kbeg + kper; k0 += 32) {
    bf16x8 bfrag = *(const bf16x8*)(wptr + k0);
#pragma unroll
    for (int mi = 0; mi < 4; ++mi) {
      bf16x8 afrag = *(const bf16x8*)(aptr[mi] + k0);
      acc[mi] = __builtin_amdgcn_mfma_f32_16x16x32_bf16(afrag, bfrag, acc[mi], 0, 0, 0);
    }
  }
  int ccol = n_base + r;
  if (ccol < N) {
#pragma unroll
    for (int mi = 0; mi < 4; ++mi) {
#pragma unroll
      for (int rr = 0; rr < 4; ++rr) {
        int crow = m_base + mi * 16 + quad * 4 + rr;
        if (crow < M) {
          size_t o = (size_t)crow * N + ccol;
          if (mode == 0)      outf[o] = acc[mi][rr];
          else if (mode == 1) outf[o] += acc[mi][rr];
          else if (mode == 2) outb[o] = f2bf(acc[mi][rr]);
          else                atomicAdd(&outf[o], acc[mi][rr]);
        }
      }
    }
  }
}

// ---------------- fused LayerNorm + in_proj GEMM ----------------
// xzt[1536][T] = inWb[1536,384] · LN(h)[T,384]^T, bf16 out.
// grid (1536/64=24, 25 token-tiles). Block stages LN'd 64x384 token tile in LDS.
__global__ __launch_bounds__(256) void gemm_ln(const float* __restrict__ h,
                                               const float* __restrict__ lw,
                                               const float* __restrict__ lb,
                                               const u16* __restrict__ Wt,
                                               u16* __restrict__ xzt) {
  __shared__ u16 atile[64][392];   // [token][k], +8 pad
  __shared__ float ps[4][64], ps2[4][64], smu[64], srs[64];
  int tid = threadIdx.x;
  int tok = tid & 63, q = tid >> 6;     // q == wave index
  int tok0 = blockIdx.y * 64;
  int tg = tok0 + tok; if (tg > T_ - 1) tg = T_ - 1;
  const float* hrow = h + (size_t)tg * DM + q * 96;

  // phase 1: stats (each thread: 96 floats of one token)
  float s = 0.f, s2 = 0.f;
#pragma unroll
  for (int i = 0; i < 24; ++i) {
    float4 v = *(const float4*)(hrow + i * 4);
    s  += v.x + v.y + v.z + v.w;
    s2 += v.x * v.x + v.y * v.y + v.z * v.z + v.w * v.w;
  }
  ps[q][tok] = s; ps2[q][tok] = s2;
  __syncthreads();
  if (tid < 64) {
    float ts  = ps[0][tid] + ps[1][tid] + ps[2][tid] + ps[3][tid];
    float ts2 = ps2[0][tid] + ps2[1][tid] + ps2[2][tid] + ps2[3][tid];
    float mu  = ts * (1.f / DM);
    float var = ts2 * (1.f / DM) - mu * mu;
    smu[tid] = mu; srs[tid] = rsqrtf(var + 1e-5f);
  }
  __syncthreads();
  // phase 2: LN'd bf16 tile into LDS
  {
    float mu = smu[tok], rs = srs[tok];
#pragma unroll
    for (int i = 0; i < 24; ++i) {
      int k = q * 96 + i * 4;
      float4 v  = *(const float4*)(hrow + i * 4);
      float4 w4 = *(const float4*)(lw + k);
      float4 b4 = *(const float4*)(lb + k);
      u16x4 rr;
      rr.x = f2bf((v.x - mu) * rs * w4.x + b4.x);
      rr.y = f2bf((v.y - mu) * rs * w4.y + b4.y);
      rr.z = f2bf((v.z - mu) * rs * w4.z + b4.z);
      rr.w = f2bf((v.w - mu) * rs * w4.w + b4.w);
      *(u16x4*)&atile[tok][k] = rr;
    }
  }
  __syncthreads();

  // MFMA: A = weights (global, K-contig), B = LN'd tokens (LDS)
  int wave = tid >> 6;
  int lane = tid & 63;
  int r = lane & 15, quad = lane >> 4;
  int m_base = blockIdx.x * 64;
  const u16* aptr[4];
#pragma unroll
  for (int mi = 0; mi < 4; ++mi) {
    aptr[mi] = Wt + (size_t)(m_base + mi * 16 + r) * DM + quad * 8;
  }
  const u16* lptr = &atile[wave * 16 + r][quad * 8];

  f32x4 acc[4] = {f32x4{0,0,0,0}, f32x4{0,0,0,0}, f32x4{0,0,0,0}, f32x4{0,0,0,0}};
#pragma unroll
  for (int k0 = 0; k0 < DM; k0 += 32) {
    bf16x8 bfrag = *(const bf16x8*)(lptr + k0);
#pragma unroll
    for (int mi = 0; mi < 4; ++mi) {
      bf16x8 afrag = *(const bf16x8*)(aptr[mi] + k0);
      acc[mi] = __builtin_amdgcn_mfma_f32_16x16x32_bf16(afrag, bfrag, acc[mi], 0, 0, 0);
    }
  }
  int ccol = tok0 + wave * 16 + r;
  if (ccol < T_) {
#pragma unroll
    for (int mi = 0; mi < 4; ++mi) {
#pragma unroll
      for (int rr2 = 0; rr2 < 4; ++rr2) {
        int crow = m_base + mi * 16 + quad * 4 + rr2;
        xzt[(size_t)crow * T_ + ccol] = f2bf(acc[mi][rr2]);
      }
    }
  }
}

// ---------------- add patch bias + positional embedding ----------------
__global__ __launch_bounds__(256) void biaspos_kernel(float* __restrict__ h,
                                                      const float* __restrict__ pb,
                                                      const float* __restrict__ pos) {
  int idx = blockIdx.x * 256 + threadIdx.x;  // t*384 + c
  int t = idx / DM, c = idx - t * DM;
  int p = (t % L_) % NPATCH;
  h[idx] += pb[c] + pos[(size_t)(1 + p) * DM + c];
}

// ---------------- LayerNorm over DM per token (final only) ----------------
__global__ __launch_bounds__(384) void ln_kernel(const float* __restrict__ x,
                                                 const float* __restrict__ w,
                                                 const float* __restrict__ b,
                                                 float* __restrict__ out_f) {
  int t = blockIdx.x;
  int i = threadIdx.x;
  float v = x[(size_t)t * DM + i];
  float s = v, s2 = v * v;
#pragma unroll
  for (int o = 32; o; o >>= 1) { s += __shfl_xor(s, o); s2 += __shfl_xor(s2, o); }
  __shared__ float ls[6], ls2[6];
  int wv = i >> 6;
  if ((i & 63) == 0) { ls[wv] = s; ls2[wv] = s2; }
  __syncthreads();
  float ts = 0.f, ts2 = 0.f;
#pragma unroll
  for (int j = 0; j < 6; ++j) { ts += ls[j]; ts2 += ls2[j]; }
  float mu  = ts * (1.f / DM);
  float var = ts2 * (1.f / DM) - mu * mu;
  float rs  = rsqrtf(var + 1e-5f);
  out_f[(size_t)t * DM + i] = (v - mu) * rs * w[i] + b[i];
}

// ---------------- causal conv3 + SiLU, d-major in, dual-layout out; zeros dbl ----------------
__global__ __launch_bounds__(256) void conv_kernel(const u16* __restrict__ xzt,
                                                   const float* __restrict__ cw,
                                                   const float* __restrict__ cb,
                                                   u16* __restrict__ xct,
                                                   u16* __restrict__ xcb,
                                                   float* __restrict__ dbl0) {
  // zero dbl (T_*56 floats) cooperatively: 300 blocks x ~294 elems
  {
    int flat = blockIdx.y * 12 + blockIdx.x;   // [0,300)
    int beg = flat * 294, end = beg + 294;
    if (end > T_ * 56) end = T_ * 56;
    for (int i = beg + threadIdx.x; i < end; i += 256) dbl0[i] = 0.f;
  }
  __shared__ u16 tile[64][66];
  int d0 = blockIdx.x * 64, t0 = blockIdx.y * 64;
  int tl = threadIdx.x & 63, dq = threadIdx.x >> 6;
  int t  = t0 + tl;
  int tc = (t < T_) ? t : T_ - 1;
  int l  = tc % L_;
#pragma unroll
  for (int i = 0; i < 16; ++i) {
    int dl = dq * 16 + i;
    int d  = d0 + dl;
    const u16* row = xzt + (size_t)d * T_ + tc;
    float acc = cb[d] + cw[d * 3 + 2] * bf2f(row[0]);
    if (l >= 1) acc += cw[d * 3 + 1] * bf2f(row[-1]);
    if (l >= 2) acc += cw[d * 3 + 0] * bf2f(row[-2]);
    float v = acc / (1.f + __expf(-acc));   // silu
    u16 bv = f2bf(v);
    if (t < T_) xct[(size_t)d * T_ + t] = bv;
    tile[dl][tl] = bv;
  }
  __syncthreads();
#pragma unroll
  for (int i = 0; i < 16; ++i) {
    int t2 = t0 + dq * 16 + i;
    if (t2 < T_) xcb[(size_t)t2 * DI + d0 + tl] = tile[tl][dq * 16 + i];
  }
}

// ---------------- chunked selective scan with fused dt-proj + silu(z) ----------------
__global__ __launch_bounds__(256) void scan_kernel(const u16* __restrict__ xct,
                                                   const u16* __restrict__ xzt,
                                                   const float* __restrict__ dbl,
                                                   const float* __restrict__ dtW,
                                                   const float* __restrict__ dtB,
                                                   const float* __restrict__ Alog,
                                                   const float* __restrict__ Dp,
                                                   u16* __restrict__ yt) {
  int bd = blockIdx.x;          // b*DI + d
  int d  = bd % DI;
  int b  = bd / DI;
  int tid = threadIdx.x;
  int n = tid & 15, c = tid >> 4;   // c in [0,16), valid for c < NC

  __shared__ float dtsh[L_];
  __shared__ float zsh[L_];
  __shared__ float Psh[NC][DS], Ssh[NC][DS], Hsh[NC][DS];
  __shared__ u16 ysh[L_];

  // cooperative: dt projection + softplus, silu(z)
  const float* wr = dtW + (size_t)d * DTR;   // block-uniform -> scalar loads
  float bias = dtB[d];
  const u16* zrow = xzt + (size_t)(DI + d) * T_ + b * L_;
  for (int l = tid; l < L_; l += 256) {
    const float* dr = dbl + (size_t)(b * L_ + l) * 56;
    float s = bias;
#pragma unroll
    for (int j = 0; j < DTR; ++j) s += dr[j] * wr[j];
    dtsh[l] = (s > 20.f) ? s : log1pf(__expf(s));
    float zv = bf2f(zrow[l]);
    zsh[l] = zv / (1.f + __expf(-zv));
  }
  float A  = -__expf(Alog[(size_t)d * DS + n]);
  float Dd = Dp[d];
  __syncthreads();

  int tb = b * L_ + c * CL;
  const u16*   xcp = xct + (size_t)d * T_ + tb;
  const float* Bp  = dbl + (size_t)tb * 56 + DTR + n;
  const float* Cp  = Bp + DS;

  float dA[CL], dBu[CL];
  if (c < NC) {
    float P = 1.f, S = 0.f;
#pragma unroll
    for (int l = 0; l < CL; ++l) {
      float dtv = dtsh[c * CL + l];        // LDS broadcast across n
      float xcv = bf2f(xcp[l]);
      float Bv  = Bp[l * 56];
      float e = __expf(dtv * A);
      float u = dtv * xcv * Bv;
      dA[l] = e; dBu[l] = u;
      P *= e;
      S = e * S + u;
    }
    Psh[c][n] = P; Ssh[c][n] = S;
  }
  __syncthreads();
  if (tid < DS) {   // thread n: serial combine over chunks
    float hh = 0.f;
#pragma unroll
    for (int cc = 0; cc < NC; ++cc) {
      Hsh[cc][tid] = hh;
      hh = Psh[cc][tid] * hh + Ssh[cc][tid];
    }
  }
  __syncthreads();
  if (c < NC) {
    float hh = Hsh[c][n];
#pragma unroll
    for (int l = 0; l < CL; ++l) {
      hh = dA[l] * hh + dBu[l];
      float p = hh * Cp[l * 56];
      p += __shfl_xor(p, 1); p += __shfl_xor(p, 2);
      p += __shfl_xor(p, 4); p += __shfl_xor(p, 8);
      if (n == 0) {
        float xcv = bf2f(xcp[l]);
        ysh[c * CL + l] = f2bf((p + Dd * xcv) * zsh[c * CL + l]);
      }
    }
  }
  __syncthreads();
  if (tid < 196) {  // 392 u16 = 196 dwords, contiguous coalesced row store
    ((u32*)(yt + (size_t)d * T_ + b * L_))[tid] = ((const u32*)ysh)[tid];
  }
}

// ---------------- y_t[d][t] -> y[t][d] bf16 tile transpose ----------------
__global__ __launch_bounds__(256) void ytr_kernel(const u16* __restrict__ yt,
                                                  u16* __restrict__ y) {
  __shared__ u16 tile[64][66];
  int d0 = blockIdx.x * 64, t0 = blockIdx.y * 64;
  int tl = threadIdx.x & 63, dq = threadIdx.x >> 6;
  int t = t0 + tl;
  int tc = (t < T_) ? t : T_ - 1;
#pragma unroll
  for (int i = 0; i < 16; ++i) {
    int dl = dq * 16 + i;
    tile[dl][tl] = yt[(size_t)(d0 + dl) * T_ + tc];
  }
  __syncthreads();
#pragma unroll
  for (int i = 0; i < 16; ++i) {
    int t2 = t0 + dq * 16 + i;
    if (t2 < T_) y[(size_t)t2 * DI + d0 + tl] = tile[tl][dq * 16 + i];
  }
}

extern "C" void kernel_launch(void* const* d_in, const int* in_sizes, int n_in,
                              void* d_out, int out_size, void* d_ws, size_t ws_size,
                              hipStream_t stream) {
  const float* z      = (const float*)d_in[0];
  const float* x      = (const float*)d_in[1];
  const float* patchW = (const float*)d_in[2];
  const float* patchB = (const float*)d_in[3];
  const float* pos    = (const float*)d_in[4];
  const float* normW  = (const float*)d_in[5];
  const float* normB  = (const float*)d_in[6];
  const float* inW    = (const float*)d_in[7];
  const float* convW  = (const float*)d_in[8];
  const float* convB  = (const float*)d_in[9];
  const float* xprojW = (const float*)d_in[10];
  const float* dtW    = (const float*)d_in[11];
  const float* dtB    = (const float*)d_in[12];
  const float* Alog   = (const float*)d_in[13];
  const float* Dpar   = (const float*)d_in[14];
  const float* outW   = (const float*)d_in[15];
  const float* fnW    = (const float*)d_in[16];
  const float* fnB    = (const float*)d_in[17];
  float* out = (float*)d_out;

  char* base = (char*)d_ws; size_t off = 0;
  auto alloc = [&](size_t bytes) {
    void* p = base + off; off = (off + bytes + 255) & ~(size_t)255; return p;
  };
  float* h    = (float*)alloc((size_t)T_ * DM * 4);
  u16*   xzt  = (u16*)  alloc((size_t)2 * DI * T_ * 2);   // [1536][T] bf16
  u16*   xct  = (u16*)  alloc((size_t)DI * T_ * 2);       // [DI][T] bf16
  u16*   xcb  = (u16*)  alloc((size_t)T_ * DI * 2);       // [T][DI] bf16
  float* dbl  = (float*)alloc((size_t)T_ * 56 * 4);
  u16*   yt   = (u16*)  alloc((size_t)DI * T_ * 2);       // [DI][T] bf16
  u16*   yb   = (u16*)  alloc((size_t)T_ * DI * 2);       // [T][DI] bf16
  u16*   imcol= (u16*)  alloc((size_t)T_ * 768 * 2);
  u16*   pwB  = (u16*)  alloc((size_t)DM * 768 * 2);
  u16*   inWb = (u16*)  alloc((size_t)DEPTH_ * 2 * DI * DM * 2);
  u16*   xpWb = (u16*)  alloc((size_t)DEPTH_ * 56 * DI * 2);
  u16*   outWb= (u16*)  alloc((size_t)DEPTH_ * DM * DI * 2);

  // one-time (per call) weight conversion fp32 -> bf16, single vectorized launch
  {
    int m0 = DM * 768 / 4;
    int m1 = DEPTH_ * 2 * DI * DM / 4;
    int m2 = DEPTH_ * 56 * DI / 4;
    int m3 = DEPTH_ * DM * DI / 4;
    int mt = m0 + m1 + m2 + m3;
    cvt4v_kernel<<<dim3((mt + 255) / 256), 256, 0, stream>>>(
        patchW, pwB, m0, inW, inWb, m1, xprojW, xpWb, m2, outW, outWb, m3);
  }

  // patch embed: im2col + GEMM + bias/pos
  imcol_kernel<<<dim3(T_ * 768 / 256), 256, 0, stream>>>(z, x, imcol);
  gemm_bf16<<<dim3((T_ + 63) / 64, DM / 64, 1), 256, 0, stream>>>(
      imcol, pwB, h, (u16*)nullptr, T_, DM, 768, 0);
  biaspos_kernel<<<dim3(T_ * DM / 256), 256, 0, stream>>>(h, patchB, pos);

  const int TG = (T_ + 63) / 64;  // 25
  for (int ly = 0; ly < DEPTH_; ++ly) {
    // fused LN + in_proj: xz_t[1536][T]
    gemm_ln<<<dim3((2 * DI) / 64, TG), 256, 0, stream>>>(
        h, normW + (size_t)ly * DM, normB + (size_t)ly * DM,
        inWb + (size_t)ly * 2 * DI * DM, xzt);
    conv_kernel<<<dim3(DI / 64, TG), 256, 0, stream>>>(
        xzt, convW + (size_t)ly * DI * 3, convB + (size_t)ly * DI, xct, xcb, dbl);
    // x_proj, K split 4-way, atomic accumulate into zeroed dbl
    gemm_bf16<<<dim3(TG, 1, 4), 256, 0, stream>>>(
        xcb, xpWb + (size_t)ly * 56 * DI, dbl, (u16*)nullptr, T_, 56, DI, 3);
    scan_kernel<<<dim3(B_ * DI), 256, 0, stream>>>(
        xct, xzt, dbl, dtW + (size_t)ly * DI * DTR, dtB + (size_t)ly * DI,
        Alog + (size_t)ly * DI * DS, Dpar + (size_t)ly * DI, yt);
    ytr_kernel<<<dim3(DI / 64, TG), 256, 0, stream>>>(yt, yb);
    // out_proj, K split 2-way, atomic accumulate residual into h
    gemm_bf16<<<dim3(TG, DM / 64, 2), 256, 0, stream>>>(
        yb, outWb + (size_t)ly * DM * DI, h, (u16*)nullptr, T_, DM, DI, 3);
  }

  ln_kernel<<<dim3(T_), dim3(DM), 0, stream>>>(h, fnW, fnB, out);
}

// Round 6
// 2901.087 us; speedup vs baseline: 3.2573x; 1.1512x over previous
//
#include <hip/hip_runtime.h>

typedef unsigned short u16;
typedef unsigned int   u32;

#define B_     4
#define L_     392
#define T_     1568   // B_*L_
#define DM     384
#define DI     768
#define DS     16
#define DTR    24
#define DEPTH_ 24
#define NPATCH 196
#define NC     14    // scan chunks
#define CL     28    // chunk length (NC*CL == L_)

// xproj_conv: K-split 8 -> 96 d's per block; LDS row pitch 104 (208B = 13*16B)
#define XKC    96
#define XPAD   104
// gemm_out: K-split 2 -> 384 d's per block; LDS row pitch 392 (784B = 49*16B)
#define OKC    384
#define OPAD   392

typedef __bf16 bf16x8 __attribute__((ext_vector_type(8)));
typedef float  f32x4  __attribute__((ext_vector_type(4)));
typedef u16    u16x4  __attribute__((ext_vector_type(4)));

__device__ __forceinline__ u16 f2bf(float f) {
  union { float f; u32 u; } v; v.f = f;
  return (u16)((v.u + 0x7fffu + ((v.u >> 16) & 1u)) >> 16);  // RNE
}
__device__ __forceinline__ float bf2f(u16 h) {
  union { u32 u; float f; } v; v.u = (u32)h << 16; return v.f;
}

// ---------------- fp32 -> bf16 bulk convert, vectorized, 4 segments ----------------
__global__ __launch_bounds__(256) void cvt4v_kernel(const float* __restrict__ s0, u16* __restrict__ o0, int m0,
                                                    const float* __restrict__ s1, u16* __restrict__ o1, int m1,
                                                    const float* __restrict__ s2, u16* __restrict__ o2, int m2,
                                                    const float* __restrict__ s3, u16* __restrict__ o3, int m3) {
  int i = blockIdx.x * 256 + threadIdx.x;   // index in float4 units
  const float* s; u16* o;
  if (i < m0)      { s = s0; o = o0; }
  else { i -= m0;
  if (i < m1)      { s = s1; o = o1; }
  else { i -= m1;
  if (i < m2)      { s = s2; o = o2; }
  else { i -= m2;
  if (i < m3)      { s = s3; o = o3; }
  else return; } } }
  float4 v = ((const float4*)s)[i];
  u16x4 r;
  r.x = f2bf(v.x); r.y = f2bf(v.y); r.z = f2bf(v.z); r.w = f2bf(v.w);
  ((u16x4*)o)[i] = r;
}

// ---------------- im2col for patch embed (both z and x) ----------------
__global__ __launch_bounds__(256) void imcol_kernel(const float* __restrict__ z,
                                                    const float* __restrict__ x,
                                                    u16* __restrict__ out) {
  int idx = blockIdx.x * 256 + threadIdx.x;        // t*768 + k
  int t = idx / 768, k = idx - t * 768;
  int b = t / L_, l = t - b * L_;
  const float* img = (l < NPATCH) ? z : x;
  int p  = (l < NPATCH) ? l : l - NPATCH;
  int py = p / 14, px = p - py * 14;
  int ic = k >> 8, rem = k & 255, i = rem >> 4, j = rem & 15;
  float v = img[((size_t)b * 3 + ic) * 50176 + (size_t)(py * 16 + i) * 224 + (px * 16 + j)];
  out[idx] = f2bf(v);
}

// ---------------- generic bf16 MFMA GEMM (patch embed only now) ----------------
__global__ __launch_bounds__(256) void gemm_bf16(const u16* __restrict__ A,
                                                 const u16* __restrict__ W,
                                                 float* __restrict__ outf,
                                                 int M, int N, int K) {
  int wave = threadIdx.x >> 6;
  int lane = threadIdx.x & 63;
  int r = lane & 15, quad = lane >> 4;
  int m_base = blockIdx.x * 64;
  int n_base = blockIdx.y * 64 + wave * 16;

  const u16* aptr[4];
#pragma unroll
  for (int mi = 0; mi < 4; ++mi) {
    int row = m_base + mi * 16 + r; if (row > M - 1) row = M - 1;
    aptr[mi] = A + (size_t)row * K + quad * 8;
  }
  int wcol = n_base + r; if (wcol > N - 1) wcol = N - 1;
  const u16* wptr = W + (size_t)wcol * K + quad * 8;

  f32x4 acc[4] = {f32x4{0,0,0,0}, f32x4{0,0,0,0}, f32x4{0,0,0,0}, f32x4{0,0,0,0}};
  for (int k0 = 0; k0 < K; k0 += 32) {
    bf16x8 bfrag = *(const bf16x8*)(wptr + k0);
#pragma unroll
    for (int mi = 0; mi < 4; ++mi) {
      bf16x8 afrag = *(const bf16x8*)(aptr[mi] + k0);
      acc[mi] = __builtin_amdgcn_mfma_f32_16x16x32_bf16(afrag, bfrag, acc[mi], 0, 0, 0);
    }
  }
  int ccol = n_base + r;
  if (ccol < N) {
#pragma unroll
    for (int mi = 0; mi < 4; ++mi) {
#pragma unroll
      for (int rr = 0; rr < 4; ++rr) {
        int crow = m_base + mi * 16 + quad * 4 + rr;
        if (crow < M) outf[(size_t)crow * N + ccol] = acc[mi][rr];
      }
    }
  }
}

// ---------------- fused LayerNorm + in_proj GEMM (+ zeroes dbl) ----------------
// xzt[1536][T] = inWb[1536,384] · LN(h)[T,384]^T, bf16 out. grid (24, 25).
__global__ __launch_bounds__(256) void gemm_ln(const float* __restrict__ h,
                                               const float* __restrict__ lw,
                                               const float* __restrict__ lb,
                                               const u16* __restrict__ Wt,
                                               u16* __restrict__ xzt,
                                               float* __restrict__ dbl0) {
  // zero dbl (T_*56 floats): 600 blocks x 147 elems
  {
    int flat = blockIdx.y * 24 + blockIdx.x;
    int beg = flat * 147, end = beg + 147;
    if (end > T_ * 56) end = T_ * 56;
    for (int i = beg + threadIdx.x; i < end; i += 256) dbl0[i] = 0.f;
  }
  __shared__ u16 atile[64][392];   // 784B row = 49*16B: aligned b128, 2-way banks
  __shared__ float ps[4][64], ps2[4][64], smu[64], srs[64];
  int tid = threadIdx.x;
  int tok = tid & 63, q = tid >> 6;
  int tok0 = blockIdx.y * 64;
  int tg = tok0 + tok; if (tg > T_ - 1) tg = T_ - 1;
  const float* hrow = h + (size_t)tg * DM + q * 96;

  float s = 0.f, s2 = 0.f;
#pragma unroll
  for (int i = 0; i < 24; ++i) {
    float4 v = *(const float4*)(hrow + i * 4);
    s  += v.x + v.y + v.z + v.w;
    s2 += v.x * v.x + v.y * v.y + v.z * v.z + v.w * v.w;
  }
  ps[q][tok] = s; ps2[q][tok] = s2;
  __syncthreads();
  if (tid < 64) {
    float ts  = ps[0][tid] + ps[1][tid] + ps[2][tid] + ps[3][tid];
    float ts2 = ps2[0][tid] + ps2[1][tid] + ps2[2][tid] + ps2[3][tid];
    float mu  = ts * (1.f / DM);
    float var = ts2 * (1.f / DM) - mu * mu;
    smu[tid] = mu; srs[tid] = rsqrtf(var + 1e-5f);
  }
  __syncthreads();
  {
    float mu = smu[tok], rs = srs[tok];
#pragma unroll
    for (int i = 0; i < 24; ++i) {
      int k = q * 96 + i * 4;
      float4 v  = *(const float4*)(hrow + i * 4);
      float4 w4 = *(const float4*)(lw + k);
      float4 b4 = *(const float4*)(lb + k);
      u16x4 rr;
      rr.x = f2bf((v.x - mu) * rs * w4.x + b4.x);
      rr.y = f2bf((v.y - mu) * rs * w4.y + b4.y);
      rr.z = f2bf((v.z - mu) * rs * w4.z + b4.z);
      rr.w = f2bf((v.w - mu) * rs * w4.w + b4.w);
      *(u16x4*)&atile[tok][k] = rr;
    }
  }
  __syncthreads();

  int wave = q, lane = tid & 63;
  int r = lane & 15, quad = lane >> 4;
  int m_base = blockIdx.x * 64;
  const u16* aptr[4];
#pragma unroll
  for (int mi = 0; mi < 4; ++mi)
    aptr[mi] = Wt + (size_t)(m_base + mi * 16 + r) * DM + quad * 8;
  const u16* lptr = &atile[wave * 16 + r][quad * 8];

  f32x4 acc[4] = {f32x4{0,0,0,0}, f32x4{0,0,0,0}, f32x4{0,0,0,0}, f32x4{0,0,0,0}};
#pragma unroll
  for (int k0 = 0; k0 < DM; k0 += 32) {
    bf16x8 bfrag = *(const bf16x8*)(lptr + k0);
#pragma unroll
    for (int mi = 0; mi < 4; ++mi) {
      bf16x8 afrag = *(const bf16x8*)(aptr[mi] + k0);
      acc[mi] = __builtin_amdgcn_mfma_f32_16x16x32_bf16(afrag, bfrag, acc[mi], 0, 0, 0);
    }
  }
  int ccol = tok0 + wave * 16 + r;
  if (ccol < T_) {
#pragma unroll
    for (int mi = 0; mi < 4; ++mi) {
#pragma unroll
      for (int rr2 = 0; rr2 < 4; ++rr2) {
        int crow = m_base + mi * 16 + quad * 4 + rr2;
        xzt[(size_t)crow * T_ + ccol] = f2bf(acc[mi][rr2]);
      }
    }
  }
}

// ---------------- fused conv3+SiLU + x_proj GEMM ----------------
// dbl[T,56] += conv(xzt)·xpW^T over d-slice. grid (25, 1, 8), atomic epilogue.
__global__ __launch_bounds__(256) void xproj_conv(const u16* __restrict__ xzt,
                                                  const float* __restrict__ cw,
                                                  const float* __restrict__ cb,
                                                  const u16* __restrict__ Wx,
                                                  float* __restrict__ dbl) {
  __shared__ u16 tile[64][XPAD];   // 208B row = 13*16B
  int t0 = blockIdx.x * 64;
  int kbeg = blockIdx.z * XKC;
  int tid = threadIdx.x;
  int tl = tid & 63, rq = tid >> 6;
  int t = t0 + tl;
  int tc = (t < T_) ? t : T_ - 1;
  int l = tc % L_;
  for (int kkb = rq * 2; kkb < XKC; kkb += 8) {
    u32 pack = 0;
#pragma unroll
    for (int ss = 0; ss < 2; ++ss) {
      int d = kbeg + kkb + ss;
      const u16* row = xzt + (size_t)d * T_ + tc;
      float acc = cb[d] + cw[d * 3 + 2] * bf2f(row[0]);
      if (l >= 1) acc += cw[d * 3 + 1] * bf2f(row[-1]);
      if (l >= 2) acc += cw[d * 3 + 0] * bf2f(row[-2]);
      float v = acc / (1.f + __expf(-acc));
      pack |= (u32)f2bf(v) << (16 * ss);
    }
    *(u32*)&tile[tl][kkb] = pack;
  }
  __syncthreads();

  int wave = tid >> 6, lane = tid & 63;
  int r = lane & 15, quad = lane >> 4;
  int wcol = wave * 16 + r; int wc = (wcol < 56) ? wcol : 55;
  const u16* wptr = Wx + (size_t)wc * DI + kbeg + quad * 8;

  f32x4 acc4[4] = {f32x4{0,0,0,0}, f32x4{0,0,0,0}, f32x4{0,0,0,0}, f32x4{0,0,0,0}};
#pragma unroll
  for (int k0 = 0; k0 < XKC; k0 += 32) {
    bf16x8 bfrag = *(const bf16x8*)(wptr + k0);
#pragma unroll
    for (int mi = 0; mi < 4; ++mi) {
      bf16x8 afrag = *(const bf16x8*)&tile[mi * 16 + r][k0 + quad * 8];
      acc4[mi] = __builtin_amdgcn_mfma_f32_16x16x32_bf16(afrag, bfrag, acc4[mi], 0, 0, 0);
    }
  }
  if (wcol < 56) {
#pragma unroll
    for (int mi = 0; mi < 4; ++mi) {
#pragma unroll
      for (int rr = 0; rr < 4; ++rr) {
        int crow = t0 + mi * 16 + quad * 4 + rr;
        if (crow < T_) atomicAdd(&dbl[(size_t)crow * 56 + wcol], acc4[mi][rr]);
      }
    }
  }
}

// ---------------- fused transpose + out_proj GEMM ----------------
// h[T,384] += y^T·outW^T over d-slice. grid (25, 6, 2), atomic epilogue.
__global__ __launch_bounds__(256) void gemm_out(const u16* __restrict__ yt,
                                                const u16* __restrict__ Wo,
                                                float* __restrict__ h) {
  __shared__ u16 tile[64][OPAD];   // 784B row = 49*16B; ~50 KB
  int t0 = blockIdx.x * 64;
  int n0 = blockIdx.y * 64;
  int kbeg = blockIdx.z * OKC;
  int tid = threadIdx.x;
  {
    int tl2 = tid & 31, rq = tid >> 5;   // 8 rows per pass
    for (int kk = rq; kk < OKC; kk += 8) {
      int d = kbeg + kk;
      u32 v = *(const u32*)(yt + (size_t)d * T_ + t0 + tl2 * 2);
      tile[tl2 * 2][kk]     = (u16)v;
      tile[tl2 * 2 + 1][kk] = (u16)(v >> 16);
    }
  }
  __syncthreads();

  int wave = tid >> 6, lane = tid & 63;
  int r = lane & 15, quad = lane >> 4;
  const u16* wptr = Wo + (size_t)(n0 + wave * 16 + r) * DI + kbeg + quad * 8;

  f32x4 acc[4] = {f32x4{0,0,0,0}, f32x4{0,0,0,0}, f32x4{0,0,0,0}, f32x4{0,0,0,0}};
#pragma unroll
  for (int k0 = 0; k0 < OKC; k0 += 32) {
    bf16x8 bfrag = *(const bf16x8*)(wptr + k0);
#pragma unroll
    for (int mi = 0; mi < 4; ++mi) {
      bf16x8 afrag = *(const bf16x8*)&tile[mi * 16 + r][k0 + quad * 8];
      acc[mi] = __builtin_amdgcn_mfma_f32_16x16x32_bf16(afrag, bfrag, acc[mi], 0, 0, 0);
    }
  }
  int ccol = n0 + wave * 16 + r;
#pragma unroll
  for (int mi = 0; mi < 4; ++mi) {
#pragma unroll
    for (int rr = 0; rr < 4; ++rr) {
      int crow = t0 + mi * 16 + quad * 4 + rr;
      if (crow < T_) atomicAdd(&h[(size_t)crow * DM + ccol], acc[mi][rr]);
    }
  }
}

// ---------------- add patch bias + positional embedding ----------------
__global__ __launch_bounds__(256) void biaspos_kernel(float* __restrict__ h,
                                                      const float* __restrict__ pb,
                                                      const float* __restrict__ pos) {
  int idx = blockIdx.x * 256 + threadIdx.x;  // t*384 + c
  int t = idx / DM, c = idx - t * DM;
  int p = (t % L_) % NPATCH;
  h[idx] += pb[c] + pos[(size_t)(1 + p) * DM + c];
}

// ---------------- LayerNorm over DM per token (final only) ----------------
__global__ __launch_bounds__(384) void ln_kernel(const float* __restrict__ x,
                                                 const float* __restrict__ w,
                                                 const float* __restrict__ b,
                                                 float* __restrict__ out_f) {
  int t = blockIdx.x;
  int i = threadIdx.x;
  float v = x[(size_t)t * DM + i];
  float s = v, s2 = v * v;
#pragma unroll
  for (int o = 32; o; o >>= 1) { s += __shfl_xor(s, o); s2 += __shfl_xor(s2, o); }
  __shared__ float ls[6], ls2[6];
  int wv = i >> 6;
  if ((i & 63) == 0) { ls[wv] = s; ls2[wv] = s2; }
  __syncthreads();
  float ts = 0.f, ts2 = 0.f;
#pragma unroll
  for (int j = 0; j < 6; ++j) { ts += ls[j]; ts2 += ls2[j]; }
  float mu  = ts * (1.f / DM);
  float var = ts2 * (1.f / DM) - mu * mu;
  float rs  = rsqrtf(var + 1e-5f);
  out_f[(size_t)t * DM + i] = (v - mu) * rs * w[i] + b[i];
}

// ---------------- chunked selective scan; recomputes conv row; fused dt/silu ----------------
__global__ __launch_bounds__(256) void scan_kernel(const u16* __restrict__ xzt,
                                                   const float* __restrict__ dbl,
                                                   const float* __restrict__ cw,
                                                   const float* __restrict__ cb,
                                                   const float* __restrict__ dtW,
                                                   const float* __restrict__ dtB,
                                                   const float* __restrict__ Alog,
                                                   const float* __restrict__ Dp,
                                                   u16* __restrict__ yt) {
  int bd = blockIdx.x;          // b*DI + d
  int d  = bd % DI;
  int b  = bd / DI;
  int tid = threadIdx.x;
  int n = tid & 15, c = tid >> 4;   // c in [0,16), valid for c < NC

  __shared__ float dtsh[L_];
  __shared__ float zsh[L_];
  __shared__ float xcsh[L_];
  __shared__ float Psh[NC][DS], Ssh[NC][DS], Hsh[NC][DS];
  __shared__ u16 ysh[L_];

  // cooperative: conv row (recompute), dt projection + softplus, silu(z)
  const float* wr = dtW + (size_t)d * DTR;   // block-uniform -> scalar loads
  float bias = dtB[d];
  float w0 = cw[d * 3 + 0], w1 = cw[d * 3 + 1], w2 = cw[d * 3 + 2], cbd = cb[d];
  const u16* xrow = xzt + (size_t)d * T_ + b * L_;
  const u16* zrow = xzt + (size_t)(DI + d) * T_ + b * L_;
  for (int l = tid; l < L_; l += 256) {
    const float* dr = dbl + (size_t)(b * L_ + l) * 56;
    float s = bias;
#pragma unroll
    for (int j = 0; j < DTR; ++j) s += dr[j] * wr[j];
    dtsh[l] = (s > 20.f) ? s : log1pf(__expf(s));
    float zv = bf2f(zrow[l]);
    zsh[l] = zv / (1.f + __expf(-zv));
    float acc = cbd + w2 * bf2f(xrow[l]);
    if (l >= 1) acc += w1 * bf2f(xrow[l - 1]);
    if (l >= 2) acc += w0 * bf2f(xrow[l - 2]);
    xcsh[l] = acc / (1.f + __expf(-acc));
  }
  float A  = -__expf(Alog[(size_t)d * DS + n]);
  float Dd = Dp[d];
  __syncthreads();

  int tb = b * L_ + c * CL;
  const float* Bp = dbl + (size_t)tb * 56 + DTR + n;
  const float* Cp = Bp + DS;

  float dA[CL], dBu[CL];
  if (c < NC) {
    float P = 1.f, S = 0.f;
#pragma unroll
    for (int l = 0; l < CL; ++l) {
      float dtv = dtsh[c * CL + l];
      float xcv = xcsh[c * CL + l];
      float Bv  = Bp[l * 56];
      float e = __expf(dtv * A);
      float u = dtv * xcv * Bv;
      dA[l] = e; dBu[l] = u;
      P *= e;
      S = e * S + u;
    }
    Psh[c][n] = P; Ssh[c][n] = S;
  }
  __syncthreads();
  if (tid < DS) {   // thread n: serial combine over chunks
    float hh = 0.f;
#pragma unroll
    for (int cc = 0; cc < NC; ++cc) {
      Hsh[cc][tid] = hh;
      hh = Psh[cc][tid] * hh + Ssh[cc][tid];
    }
  }
  __syncthreads();
  if (c < NC) {
    float hh = Hsh[c][n];
#pragma unroll
    for (int l = 0; l < CL; ++l) {
      hh = dA[l] * hh + dBu[l];
      float p = hh * Cp[l * 56];
      p += __shfl_xor(p, 1); p += __shfl_xor(p, 2);
      p += __shfl_xor(p, 4); p += __shfl_xor(p, 8);
      if (n == 0) {
        int ll = c * CL + l;
        ysh[ll] = f2bf((p + Dd * xcsh[ll]) * zsh[ll]);
      }
    }
  }
  __syncthreads();
  if (tid < 196) {  // 392 u16 = 196 dwords, contiguous coalesced row store
    ((u32*)(yt + (size_t)d * T_ + b * L_))[tid] = ((const u32*)ysh)[tid];
  }
}

extern "C" void kernel_launch(void* const* d_in, const int* in_sizes, int n_in,
                              void* d_out, int out_size, void* d_ws, size_t ws_size,
                              hipStream_t stream) {
  const float* z      = (const float*)d_in[0];
  const float* x      = (const float*)d_in[1];
  const float* patchW = (const float*)d_in[2];
  const float* patchB = (const float*)d_in[3];
  const float* pos    = (const float*)d_in[4];
  const float* normW  = (const float*)d_in[5];
  const float* normB  = (const float*)d_in[6];
  const float* inW    = (const float*)d_in[7];
  const float* convW  = (const float*)d_in[8];
  const float* convB  = (const float*)d_in[9];
  const float* xprojW = (const float*)d_in[10];
  const float* dtW    = (const float*)d_in[11];
  const float* dtB    = (const float*)d_in[12];
  const float* Alog   = (const float*)d_in[13];
  const float* Dpar   = (const float*)d_in[14];
  const float* outW   = (const float*)d_in[15];
  const float* fnW    = (const float*)d_in[16];
  const float* fnB    = (const float*)d_in[17];
  float* out = (float*)d_out;

  char* base = (char*)d_ws; size_t off = 0;
  auto alloc = [&](size_t bytes) {
    void* p = base + off; off = (off + bytes + 255) & ~(size_t)255; return p;
  };
  float* h    = (float*)alloc((size_t)T_ * DM * 4);
  u16*   xzt  = (u16*)  alloc((size_t)2 * DI * T_ * 2);   // [1536][T] bf16
  float* dbl  = (float*)alloc((size_t)T_ * 56 * 4);
  u16*   yt   = (u16*)  alloc((size_t)DI * T_ * 2);       // [DI][T] bf16
  u16*   imcol= (u16*)  alloc((size_t)T_ * 768 * 2);
  u16*   pwB  = (u16*)  alloc((size_t)DM * 768 * 2);
  u16*   inWb = (u16*)  alloc((size_t)DEPTH_ * 2 * DI * DM * 2);
  u16*   xpWb = (u16*)  alloc((size_t)DEPTH_ * 56 * DI * 2);
  u16*   outWb= (u16*)  alloc((size_t)DEPTH_ * DM * DI * 2);

  // one-time (per call) weight conversion fp32 -> bf16, single vectorized launch
  {
    int m0 = DM * 768 / 4;
    int m1 = DEPTH_ * 2 * DI * DM / 4;
    int m2 = DEPTH_ * 56 * DI / 4;
    int m3 = DEPTH_ * DM * DI / 4;
    int mt = m0 + m1 + m2 + m3;
    cvt4v_kernel<<<dim3((mt + 255) / 256), 256, 0, stream>>>(
        patchW, pwB, m0, inW, inWb, m1, xprojW, xpWb, m2, outW, outWb, m3);
  }

  // patch embed: im2col + GEMM + bias/pos
  imcol_kernel<<<dim3(T_ * 768 / 256), 256, 0, stream>>>(z, x, imcol);
  gemm_bf16<<<dim3((T_ + 63) / 64, DM / 64), 256, 0, stream>>>(
      imcol, pwB, h, T_, DM, 768);
  biaspos_kernel<<<dim3(T_ * DM / 256), 256, 0, stream>>>(h, patchB, pos);

  const int TG = (T_ + 63) / 64;  // 25
  for (int ly = 0; ly < DEPTH_; ++ly) {
    gemm_ln<<<dim3((2 * DI) / 64, TG), 256, 0, stream>>>(
        h, normW + (size_t)ly * DM, normB + (size_t)ly * DM,
        inWb + (size_t)ly * 2 * DI * DM, xzt, dbl);
    xproj_conv<<<dim3(TG, 1, DI / XKC), 256, 0, stream>>>(
        xzt, convW + (size_t)ly * DI * 3, convB + (size_t)ly * DI,
        xpWb + (size_t)ly * 56 * DI, dbl);
    scan_kernel<<<dim3(B_ * DI), 256, 0, stream>>>(
        xzt, dbl, convW + (size_t)ly * DI * 3, convB + (size_t)ly * DI,
        dtW + (size_t)ly * DI * DTR, dtB + (size_t)ly * DI,
        Alog + (size_t)ly * DI * DS, Dpar + (size_t)ly * DI, yt);
    gemm_out<<<dim3(TG, DM / 64, DI / OKC), 256, 0, stream>>>(
        yt, outWb + (size_t)ly * DM * DI, h);
  }

  ln_kernel<<<dim3(T_), dim3(DM), 0, stream>>>(h, fnW, fnB, out);
}